// Round 1
// baseline (2492.250 us; speedup 1.0000x reference)
//
#include <hip/hip_runtime.h>
#include <hip/hip_bf16.h>
#include <math.h>

// ---------------------------------------------------------------------------
// GATNet (really a GCN pair scorer), fp32 baseline.
// Pipeline:
//   x1 = max(cid@W2 + b2 - thr, 0)                 [30000, 881]
//   x2 = relu(x1@W3 + b3)                          [30000, 256]
//   CSR build from link_edge (+implicit self loops handled analytically)
//   5x GCN layer: hW = h@W;  h' = elu(dinv[n]*(sum_s dinv[s]*hW[s]
//                                    + dinv[n]*hW[n]) + b)
//   pair: xc = normalize(concat(h[i1], h[i2]))     [4096, 256]
//   fc1(relu) -> fc2(relu) -> fc3(relu) -> out     [4096, 2]
// ---------------------------------------------------------------------------

#define NNODES 30000
#define NEDGES 480000
#define NPAIRS 4096

// ---------------- graph prep ----------------

__global__ void k_count(const int* __restrict__ dst, unsigned* __restrict__ cnt, int E) {
    int e = blockIdx.x * blockDim.x + threadIdx.x;
    if (e < E) atomicAdd(&cnt[dst[e]], 1u);
}

__global__ void k_dinv(const unsigned* __restrict__ cnt, float* __restrict__ dinv, int N) {
    int n = blockIdx.x * blockDim.x + threadIdx.x;
    if (n < N) {
        float deg = (float)(cnt[n] + 1u);   // +1 self loop, always > 0
        dinv[n] = 1.0f / sqrtf(deg);
    }
}

// single-block inclusive scan -> rowptr (exclusive prefix, rowptr[0]=0)
__global__ void k_scan(const unsigned* __restrict__ cnt, unsigned* __restrict__ rowptr, int N) {
    __shared__ unsigned buf[1024];
    __shared__ unsigned carry_s;
    const int tid = threadIdx.x;
    if (tid == 0) { carry_s = 0; rowptr[0] = 0; }
    __syncthreads();
    for (int base = 0; base < N; base += 1024) {
        int i = base + tid;
        unsigned v = (i < N) ? cnt[i] : 0u;
        buf[tid] = v;
        __syncthreads();
        for (int off = 1; off < 1024; off <<= 1) {
            unsigned t = (tid >= off) ? buf[tid - off] : 0u;
            __syncthreads();
            buf[tid] += t;
            __syncthreads();
        }
        unsigned c = carry_s;
        if (i < N) rowptr[i + 1] = c + buf[tid];
        __syncthreads();
        if (tid == 1023) carry_s = c + buf[1023];
        __syncthreads();
    }
}

__global__ void k_fill(const int* __restrict__ src, const int* __restrict__ dst,
                       const unsigned* __restrict__ rowptr, unsigned* __restrict__ cursor,
                       int* __restrict__ colsrc, int E) {
    int e = blockIdx.x * blockDim.x + threadIdx.x;
    if (e < E) {
        int d = dst[e];
        unsigned p = atomicAdd(&cursor[d], 1u);
        colsrc[rowptr[d] + p] = src[e];
    }
}

// ---------------- GEMM (f32, 64x64 tile, 4x4 micro) ----------------
// EPI: 0 = none (no bias), 1 = relu(z + b), 2 = max(z + b - thr, 0)

template <int EPI>
__global__ __launch_bounds__(256) void k_gemm(
    const float* __restrict__ A, const float* __restrict__ W,
    const float* __restrict__ bias, const float* __restrict__ thr_p,
    float* __restrict__ C, int M, int N, int K) {
    __shared__ alignas(16) float As[16][68];
    __shared__ alignas(16) float Ws[16][64];
    const int t = threadIdx.x;
    const int tx = t & 15, ty = t >> 4;
    const int bm = blockIdx.x << 6;
    const int bn = blockIdx.y << 6;
    const int a_k = t & 15, a_r = t >> 4;
    const int w_n = t & 63, w_k = t >> 6;
    float acc[4][4] = {};

    for (int k0 = 0; k0 < K; k0 += 16) {
#pragma unroll
        for (int i = 0; i < 4; ++i) {
            int m = a_r + (i << 4);
            int gr = bm + m, gk = k0 + a_k;
            float v = 0.f;
            if (gr < M && gk < K) v = A[(size_t)gr * K + gk];
            As[a_k][m] = v;
        }
#pragma unroll
        for (int i = 0; i < 4; ++i) {
            int kk = w_k + (i << 2);
            int gk = k0 + kk, gn = bn + w_n;
            float v = 0.f;
            if (gk < K && gn < N) v = W[(size_t)gk * N + gn];
            Ws[kk][w_n] = v;
        }
        __syncthreads();
#pragma unroll
        for (int kk = 0; kk < 16; ++kk) {
            const float4 av = *reinterpret_cast<const float4*>(&As[kk][ty << 2]);
            const float4 bv = *reinterpret_cast<const float4*>(&Ws[kk][tx << 2]);
            const float a0 = av.x, a1 = av.y, a2 = av.z, a3 = av.w;
            const float b0 = bv.x, b1 = bv.y, b2 = bv.z, b3 = bv.w;
            acc[0][0] += a0 * b0; acc[0][1] += a0 * b1; acc[0][2] += a0 * b2; acc[0][3] += a0 * b3;
            acc[1][0] += a1 * b0; acc[1][1] += a1 * b1; acc[1][2] += a1 * b2; acc[1][3] += a1 * b3;
            acc[2][0] += a2 * b0; acc[2][1] += a2 * b1; acc[2][2] += a2 * b2; acc[2][3] += a2 * b3;
            acc[3][0] += a3 * b0; acc[3][1] += a3 * b1; acc[3][2] += a3 * b2; acc[3][3] += a3 * b3;
        }
        __syncthreads();
    }

    float thr = 0.f;
    if (EPI == 2) thr = *thr_p;
#pragma unroll
    for (int i = 0; i < 4; ++i) {
        int gr = bm + (ty << 2) + i;
        if (gr >= M) continue;
#pragma unroll
        for (int j = 0; j < 4; ++j) {
            int gn = bn + (tx << 2) + j;
            if (gn >= N) continue;
            float z = acc[i][j];
            if (EPI >= 1) z += bias[gn];
            if (EPI == 1) z = fmaxf(z, 0.f);
            else if (EPI == 2) z = fmaxf(z - thr, 0.f);
            C[(size_t)gr * N + gn] = z;
        }
    }
}

// ---------------- GCN aggregation (gather over CSR, fused bias+ELU) --------
// out[n,f] = elu( dinv[n]*( sum_{s in N(n)} dinv[s]*hW[s,f] + dinv[n]*hW[n,f] ) + b[f] )

template <int FV>  // FV = F/64
__global__ __launch_bounds__(256) void k_agg(
    const float* __restrict__ hW, const float* __restrict__ dinv,
    const unsigned* __restrict__ rowptr, const int* __restrict__ colsrc,
    const float* __restrict__ bias, float* __restrict__ out, int N) {
    const int wave = threadIdx.x >> 6;
    const int lane = threadIdx.x & 63;
    const int n = blockIdx.x * 4 + wave;
    if (n >= N) return;
    const int F = FV * 64;
    const float dn = dinv[n];
    float acc[FV];
    const float* row = hW + (size_t)n * F;
#pragma unroll
    for (int j = 0; j < FV; ++j) acc[j] = dn * row[lane + 64 * j];
    const unsigned beg = rowptr[n], end = rowptr[n + 1];
    for (unsigned idx = beg; idx < end; ++idx) {
        int s = colsrc[idx];
        float wsc = dinv[s];
        const float* r2 = hW + (size_t)s * F;
#pragma unroll
        for (int j = 0; j < FV; ++j) acc[j] += wsc * r2[lane + 64 * j];
    }
#pragma unroll
    for (int j = 0; j < FV; ++j) {
        float z = dn * acc[j] + bias[lane + 64 * j];
        out[(size_t)n * F + lane + 64 * j] = (z > 0.f) ? z : expm1f(z);
    }
}

// ---------------- pair readout ----------------

__global__ __launch_bounds__(256) void k_pairs(
    const float* __restrict__ h, const int* __restrict__ i1, const int* __restrict__ i2,
    float* __restrict__ xc, int B) {
    const int wave = threadIdx.x >> 6;
    const int lane = threadIdx.x & 63;
    const int p = blockIdx.x * 4 + wave;
    if (p >= B) return;
    const int a = i1[p], b = i2[p];
    float v0 = h[(size_t)a * 128 + lane];
    float v1 = h[(size_t)a * 128 + 64 + lane];
    float v2 = h[(size_t)b * 128 + lane];
    float v3 = h[(size_t)b * 128 + 64 + lane];
    float ss = v0 * v0 + v1 * v1 + v2 * v2 + v3 * v3;
#pragma unroll
    for (int o = 32; o > 0; o >>= 1) ss += __shfl_xor(ss, o, 64);
    float nrm = sqrtf(ss);
    float scale = 1.0f / fmaxf(nrm, 1e-12f);
    float* o = xc + (size_t)p * 256;
    o[lane] = v0 * scale;
    o[64 + lane] = v1 * scale;
    o[128 + lane] = v2 * scale;
    o[192 + lane] = v3 * scale;
}

__global__ __launch_bounds__(256) void k_out(
    const float* __restrict__ x, const float* __restrict__ W, const float* __restrict__ b,
    float* __restrict__ out, int B) {
    const int wave = threadIdx.x >> 6;
    const int lane = threadIdx.x & 63;
    const int p = blockIdx.x * 4 + wave;
    if (p >= B) return;
    float v = x[(size_t)p * 64 + lane];
    float s0 = v * W[lane * 2 + 0];
    float s1 = v * W[lane * 2 + 1];
#pragma unroll
    for (int o = 32; o > 0; o >>= 1) {
        s0 += __shfl_xor(s0, o, 64);
        s1 += __shfl_xor(s1, o, 64);
    }
    if (lane == 0) {
        out[p * 2 + 0] = s0 + b[0];
        out[p * 2 + 1] = s1 + b[1];
    }
}

// ---------------- launcher ----------------

extern "C" void kernel_launch(void* const* d_in, const int* in_sizes, int n_in,
                              void* d_out, int out_size, void* d_ws, size_t ws_size,
                              hipStream_t stream) {
    const float* cid = (const float*)d_in[0];
    const int* le   = (const int*)d_in[1];     // [2, E] int32 (harness normalizes ints)
    const int* i1   = (const int*)d_in[2];
    const int* i2   = (const int*)d_in[3];
    const float* thr = (const float*)d_in[4];
    const float* W2 = (const float*)d_in[5];  const float* b2 = (const float*)d_in[6];
    const float* W3 = (const float*)d_in[7];  const float* b3 = (const float*)d_in[8];
    const float* gW[5] = {(const float*)d_in[9],  (const float*)d_in[11], (const float*)d_in[13],
                          (const float*)d_in[15], (const float*)d_in[17]};
    const float* gB[5] = {(const float*)d_in[10], (const float*)d_in[12], (const float*)d_in[14],
                          (const float*)d_in[16], (const float*)d_in[18]};
    const float* fc1W = (const float*)d_in[19]; const float* fc1b = (const float*)d_in[20];
    const float* fc2W = (const float*)d_in[21]; const float* fc2b = (const float*)d_in[22];
    const float* fc3W = (const float*)d_in[23]; const float* fc3b = (const float*)d_in[24];
    const float* oW   = (const float*)d_in[25]; const float* ob   = (const float*)d_in[26];

    const int N = NNODES, E = NEDGES, B = NPAIRS;

    // workspace layout (bytes, 256-aligned)
    char* ws = (char*)d_ws;
    unsigned* cnt    = (unsigned*)(ws + 0);          // 120000
    unsigned* cursor = (unsigned*)(ws + 120064);     // 120000
    unsigned* rowptr = (unsigned*)(ws + 240128);     // 120004
    int*      colsrc = (int*)     (ws + 360192);     // 1920000
    float*    dinv   = (float*)   (ws + 2280192);    // 120000
    float*    x1     = (float*)   (ws + 2400256);    // 105,720,000 (30000*881*4)
    float*    hW     = x1;                           // reuse (after x1 consumed)
    float*    hN     = (float*)   (ws + 2400256 + 30720000);
    float*    x2     = (float*)   (ws + 108120256);  // 30,720,000
    float*    xc     = (float*)   (ws + 138840256);  // 4,194,304
    float*    t1     = (float*)   (ws + 143034560);  // 16,777,216
    float*    t3     = (float*)   (ws + 159811776);  // 1,048,576
    float*    t2     = xc;                           // reuse (xc dead after fc1)

    // --- graph prep ---
    hipMemsetAsync(cnt, 0, N * sizeof(unsigned), stream);
    hipMemsetAsync(cursor, 0, N * sizeof(unsigned), stream);
    k_count<<<(E + 255) / 256, 256, 0, stream>>>(le + E, cnt, E);
    k_dinv<<<(N + 255) / 256, 256, 0, stream>>>(cnt, dinv, N);
    k_scan<<<1, 1024, 0, stream>>>(cnt, rowptr, N);
    k_fill<<<(E + 255) / 256, 256, 0, stream>>>(le, le + E, rowptr, cursor, colsrc, E);

    dim3 blk(256);
    const int MB = (N + 63) / 64;  // 469

    // --- BasicBlock1 ---
    k_gemm<2><<<dim3(MB, 14), blk, 0, stream>>>(cid, W2, b2, thr, x1, N, 881, 881);
    k_gemm<1><<<dim3(MB, 4),  blk, 0, stream>>>(x1, W3, b3, nullptr, x2, N, 256, 881);

    // --- 5 GCN layers (ping-pong x2 <-> hN, hW scratch) ---
    const int fin[5]  = {256, 256, 256, 256, 128};
    const int fout[5] = {256, 256, 256, 128, 128};
    float* outs[5] = {hN, x2, hN, x2, hN};
    float* hcur = x2;
    for (int l = 0; l < 5; ++l) {
        k_gemm<0><<<dim3(MB, fout[l] / 64), blk, 0, stream>>>(hcur, gW[l], nullptr, nullptr,
                                                              hW, N, fout[l], fin[l]);
        if (fout[l] == 256)
            k_agg<4><<<(N + 3) / 4, 256, 0, stream>>>(hW, dinv, rowptr, colsrc, gB[l], outs[l], N);
        else
            k_agg<2><<<(N + 3) / 4, 256, 0, stream>>>(hW, dinv, rowptr, colsrc, gB[l], outs[l], N);
        hcur = outs[l];
    }

    // --- pair head ---
    k_pairs<<<(B + 3) / 4, 256, 0, stream>>>(hcur, i1, i2, xc, B);
    k_gemm<1><<<dim3(64, 16), blk, 0, stream>>>(xc, fc1W, fc1b, nullptr, t1, B, 1024, 256);
    k_gemm<1><<<dim3(64, 4),  blk, 0, stream>>>(t1, fc2W, fc2b, nullptr, t2, B, 256, 1024);
    k_gemm<1><<<dim3(64, 1),  blk, 0, stream>>>(t2, fc3W, fc3b, nullptr, t3, B, 64, 256);
    k_out<<<(B + 3) / 4, 256, 0, stream>>>(t3, oW, ob, (float*)d_out, B);
}

// Round 2
// 1668.957 us; speedup vs baseline: 1.4933x; 1.4933x over previous
//
#include <hip/hip_runtime.h>
#include <hip/hip_bf16.h>
#include <math.h>

// ---------------------------------------------------------------------------
// GCN pair scorer. This round: all GEMMs moved to bf16 hi/lo split MFMA
// (3-product: Ah*Bh + Al*Bh + Ah*Bl => ~fp32 accuracy at MFMA rate).
// 128x128 tile, 4 waves, BK=32, mfma_f32_16x16x32_bf16, register staging.
// Activations flow as bf16 hi/lo pairs produced by GEMM/agg epilogues.
// ---------------------------------------------------------------------------

#define NNODES 30000
#define NEDGES 480000
#define NPAIRS 4096
#define MP 30080  // node rows padded to multiple of 128 for A-tile staging

typedef __attribute__((ext_vector_type(8))) short short8;
typedef __attribute__((ext_vector_type(4))) float f32x4;

__device__ __forceinline__ unsigned short f2bf(float x) {
    union { float f; unsigned u; } v; v.f = x;
    unsigned u = v.u;
    return (unsigned short)((u + 0x7FFFu + ((u >> 16) & 1u)) >> 16);
}
__device__ __forceinline__ float bf2f(unsigned short h) {
    union { float f; unsigned u; } v; v.u = ((unsigned)h) << 16;
    return v.f;
}

// ---------------- graph prep ----------------

__global__ void k_count(const int* __restrict__ dst, unsigned* __restrict__ cnt, int E) {
    int e = blockIdx.x * blockDim.x + threadIdx.x;
    if (e < E) atomicAdd(&cnt[dst[e]], 1u);
}

__global__ void k_dinv(const unsigned* __restrict__ cnt, float* __restrict__ dinv, int N) {
    int n = blockIdx.x * blockDim.x + threadIdx.x;
    if (n < N) {
        float deg = (float)(cnt[n] + 1u);
        dinv[n] = 1.0f / sqrtf(deg);
    }
}

__global__ void k_scan(const unsigned* __restrict__ cnt, unsigned* __restrict__ rowptr, int N) {
    __shared__ unsigned buf[1024];
    __shared__ unsigned carry_s;
    const int tid = threadIdx.x;
    if (tid == 0) { carry_s = 0; rowptr[0] = 0; }
    __syncthreads();
    for (int base = 0; base < N; base += 1024) {
        int i = base + tid;
        unsigned v = (i < N) ? cnt[i] : 0u;
        buf[tid] = v;
        __syncthreads();
        for (int off = 1; off < 1024; off <<= 1) {
            unsigned t = (tid >= off) ? buf[tid - off] : 0u;
            __syncthreads();
            buf[tid] += t;
            __syncthreads();
        }
        unsigned c = carry_s;
        if (i < N) rowptr[i + 1] = c + buf[tid];
        __syncthreads();
        if (tid == 1023) carry_s = c + buf[1023];
        __syncthreads();
    }
}

__global__ void k_fill(const int* __restrict__ src, const int* __restrict__ dst,
                       const unsigned* __restrict__ rowptr, unsigned* __restrict__ cursor,
                       int* __restrict__ colsrc, int E) {
    int e = blockIdx.x * blockDim.x + threadIdx.x;
    if (e < E) {
        int d = dst[e];
        unsigned p = atomicAdd(&cursor[d], 1u);
        colsrc[rowptr[d] + p] = src[e];
    }
}

// ---------------- weight conversion: W[K][N] f32 -> Wt[Np][Kp] bf16 hi/lo ---

__global__ void k_wconv(const float* __restrict__ W, unsigned short* __restrict__ Th,
                        unsigned short* __restrict__ Tl, int K, int N, int Kp, int Np) {
    int idx = blockIdx.x * blockDim.x + threadIdx.x;
    if (idx >= Np * Kp) return;
    int n = idx / Kp, k = idx - n * Kp;
    float v = (n < N && k < K) ? W[(size_t)k * N + n] : 0.f;
    unsigned short h = f2bf(v);
    Th[idx] = h;
    Tl[idx] = f2bf(v - bf2f(h));
}

// ---------------- split-bf16 MFMA GEMM -------------------------------------
// ASRC: 0 = f32 A (convert during staging, bounds-checked), 1 = bf16 pair A
// EPI : 0 = none, 1 = relu(z+bias), 2 = max(z+bias-thr, 0)
// OUTM: 0 = f32 C, 1 = bf16 hi/lo pair C (cols >= Ntrue zeroed)

template <int ASRC, int EPI, int OUTM>
__global__ __launch_bounds__(256) void k_mgemm(
    const float* __restrict__ Af, int ldAf, int Ktrue,
    const unsigned short* __restrict__ Ahi, const unsigned short* __restrict__ Alo, int ldA,
    const unsigned short* __restrict__ Bhi, const unsigned short* __restrict__ Blo,
    const float* __restrict__ bias, const float* __restrict__ thrp,
    float* __restrict__ Cf, unsigned short* __restrict__ Chi, unsigned short* __restrict__ Clo,
    int ldC, int M, int Ntrue, int K) {
    __shared__ alignas(16) unsigned short Ah[128 * 32];
    __shared__ alignas(16) unsigned short Al[128 * 32];
    __shared__ alignas(16) unsigned short Bh[128 * 32];
    __shared__ alignas(16) unsigned short Bl[128 * 32];
    const int t = threadIdx.x;
    const int lane = t & 63, w = t >> 6;
    const int wr = w >> 1, wc = w & 1;
    const int r16 = lane & 15, kg = lane >> 4;
    const int bm = blockIdx.x * 128, bn = blockIdx.y * 128;
    f32x4 acc[4][4] = {};

    for (int k0 = 0; k0 < K; k0 += 32) {
        if (ASRC == 0) {
            const int c = t & 31, r0 = t >> 5;
            const int gk = k0 + c;
            const bool kok = gk < Ktrue;
#pragma unroll
            for (int i = 0; i < 16; ++i) {
                int r = r0 + i * 8;
                int gm = bm + r;
                float v = (kok && gm < M) ? Af[(size_t)gm * ldAf + gk] : 0.f;
                unsigned short h = f2bf(v);
                Ah[r * 32 + c] = h;
                Al[r * 32 + c] = f2bf(v - bf2f(h));
            }
        } else {
#pragma unroll
            for (int i = 0; i < 2; ++i) {
                int e = (t + i * 256) * 8;
                int r = e >> 5, c = e & 31;
                size_t g = (size_t)(bm + r) * ldA + k0 + c;
                *(short8*)&Ah[e] = *(const short8*)&Ahi[g];
                *(short8*)&Al[e] = *(const short8*)&Alo[g];
            }
        }
#pragma unroll
        for (int i = 0; i < 2; ++i) {
            int e = (t + i * 256) * 8;
            int r = e >> 5, c = e & 31;
            size_t g = (size_t)(bn + r) * K + k0 + c;
            *(short8*)&Bh[e] = *(const short8*)&Bhi[g];
            *(short8*)&Bl[e] = *(const short8*)&Blo[g];
        }
        __syncthreads();
        short8 a_h[4], a_l[4], b_h[4], b_l[4];
#pragma unroll
        for (int mi = 0; mi < 4; ++mi) {
            int off = (wr * 64 + mi * 16 + r16) * 32 + kg * 8;
            a_h[mi] = *(const short8*)&Ah[off];
            a_l[mi] = *(const short8*)&Al[off];
        }
#pragma unroll
        for (int ni = 0; ni < 4; ++ni) {
            int off = (wc * 64 + ni * 16 + r16) * 32 + kg * 8;
            b_h[ni] = *(const short8*)&Bh[off];
            b_l[ni] = *(const short8*)&Bl[off];
        }
#pragma unroll
        for (int mi = 0; mi < 4; ++mi)
#pragma unroll
            for (int ni = 0; ni < 4; ++ni) {
                acc[mi][ni] = __builtin_amdgcn_mfma_f32_16x16x32_bf16(a_h[mi], b_h[ni], acc[mi][ni], 0, 0, 0);
                acc[mi][ni] = __builtin_amdgcn_mfma_f32_16x16x32_bf16(a_l[mi], b_h[ni], acc[mi][ni], 0, 0, 0);
                acc[mi][ni] = __builtin_amdgcn_mfma_f32_16x16x32_bf16(a_h[mi], b_l[ni], acc[mi][ni], 0, 0, 0);
            }
        __syncthreads();
    }

    const float thr = (EPI == 2) ? *thrp : 0.f;
#pragma unroll
    for (int mi = 0; mi < 4; ++mi) {
#pragma unroll
        for (int ni = 0; ni < 4; ++ni) {
            const int n = bn + wc * 64 + ni * 16 + r16;
#pragma unroll
            for (int i = 0; i < 4; ++i) {
                const int m = bm + wr * 64 + mi * 16 + kg * 4 + i;
                if (m >= M) continue;
                float z = acc[mi][ni][i];
                if (EPI >= 1) {
                    z += (n < Ntrue) ? bias[n] : 0.f;
                    z = (EPI == 1) ? fmaxf(z, 0.f) : fmaxf(z - thr, 0.f);
                }
                if (OUTM == 0) {
                    if (n < Ntrue) Cf[(size_t)m * ldC + n] = z;
                } else {
                    if (n < ldC) {
                        if (n >= Ntrue) z = 0.f;
                        unsigned short h = f2bf(z);
                        size_t o = (size_t)m * ldC + n;
                        Chi[o] = h;
                        Clo[o] = f2bf(z - bf2f(h));
                    }
                }
            }
        }
    }
}

// ---------------- GCN aggregation (CSR gather, bias+ELU fused) -------------
// WB=1: write bf16 hi/lo pair; WB=0: write f32

template <int FV, int WB>
__global__ __launch_bounds__(256) void k_agg(
    const float* __restrict__ hW, const float* __restrict__ dinv,
    const unsigned* __restrict__ rowptr, const int* __restrict__ colsrc,
    const float* __restrict__ bias, float* __restrict__ outf,
    unsigned short* __restrict__ oh, unsigned short* __restrict__ ol, int N) {
    const int wave = threadIdx.x >> 6;
    const int lane = threadIdx.x & 63;
    const int n = blockIdx.x * 4 + wave;
    if (n >= N) return;
    const int F = FV * 64;
    const float dn = dinv[n];
    float acc[FV];
    const float* row = hW + (size_t)n * F;
#pragma unroll
    for (int j = 0; j < FV; ++j) acc[j] = dn * row[lane + 64 * j];
    const unsigned beg = rowptr[n], end = rowptr[n + 1];
    for (unsigned idx = beg; idx < end; ++idx) {
        int s = colsrc[idx];
        float wsc = dinv[s];
        const float* r2 = hW + (size_t)s * F;
#pragma unroll
        for (int j = 0; j < FV; ++j) acc[j] += wsc * r2[lane + 64 * j];
    }
#pragma unroll
    for (int j = 0; j < FV; ++j) {
        float z = dn * acc[j] + bias[lane + 64 * j];
        z = (z > 0.f) ? z : expm1f(z);
        size_t o = (size_t)n * F + lane + 64 * j;
        if (WB) {
            unsigned short h = f2bf(z);
            oh[o] = h;
            ol[o] = f2bf(z - bf2f(h));
        } else {
            outf[o] = z;
        }
    }
}

// ---------------- pair readout ----------------

__global__ __launch_bounds__(256) void k_pairs(
    const float* __restrict__ h, const int* __restrict__ i1, const int* __restrict__ i2,
    unsigned short* __restrict__ xh, unsigned short* __restrict__ xl, int B) {
    const int wave = threadIdx.x >> 6;
    const int lane = threadIdx.x & 63;
    const int p = blockIdx.x * 4 + wave;
    if (p >= B) return;
    const int a = i1[p], b = i2[p];
    float v0 = h[(size_t)a * 128 + lane];
    float v1 = h[(size_t)a * 128 + 64 + lane];
    float v2 = h[(size_t)b * 128 + lane];
    float v3 = h[(size_t)b * 128 + 64 + lane];
    float ss = v0 * v0 + v1 * v1 + v2 * v2 + v3 * v3;
#pragma unroll
    for (int o = 32; o > 0; o >>= 1) ss += __shfl_xor(ss, o, 64);
    float scale = 1.0f / fmaxf(sqrtf(ss), 1e-12f);
    size_t o = (size_t)p * 256;
    float vv[4] = {v0 * scale, v1 * scale, v2 * scale, v3 * scale};
#pragma unroll
    for (int j = 0; j < 4; ++j) {
        unsigned short hh = f2bf(vv[j]);
        xh[o + j * 64 + lane] = hh;
        xl[o + j * 64 + lane] = f2bf(vv[j] - bf2f(hh));
    }
}

__global__ __launch_bounds__(256) void k_out(
    const float* __restrict__ x, const float* __restrict__ W, const float* __restrict__ b,
    float* __restrict__ out, int B) {
    const int wave = threadIdx.x >> 6;
    const int lane = threadIdx.x & 63;
    const int p = blockIdx.x * 4 + wave;
    if (p >= B) return;
    float v = x[(size_t)p * 64 + lane];
    float s0 = v * W[lane * 2 + 0];
    float s1 = v * W[lane * 2 + 1];
#pragma unroll
    for (int o = 32; o > 0; o >>= 1) {
        s0 += __shfl_xor(s0, o, 64);
        s1 += __shfl_xor(s1, o, 64);
    }
    if (lane == 0) {
        out[p * 2 + 0] = s0 + b[0];
        out[p * 2 + 1] = s1 + b[1];
    }
}

// ---------------- launcher ----------------

extern "C" void kernel_launch(void* const* d_in, const int* in_sizes, int n_in,
                              void* d_out, int out_size, void* d_ws, size_t ws_size,
                              hipStream_t stream) {
    const float* cid = (const float*)d_in[0];
    const int* le   = (const int*)d_in[1];
    const int* i1   = (const int*)d_in[2];
    const int* i2   = (const int*)d_in[3];
    const float* thr = (const float*)d_in[4];
    const float* W2 = (const float*)d_in[5];  const float* b2 = (const float*)d_in[6];
    const float* W3 = (const float*)d_in[7];  const float* b3 = (const float*)d_in[8];
    const float* gW[5] = {(const float*)d_in[9],  (const float*)d_in[11], (const float*)d_in[13],
                          (const float*)d_in[15], (const float*)d_in[17]};
    const float* gB[5] = {(const float*)d_in[10], (const float*)d_in[12], (const float*)d_in[14],
                          (const float*)d_in[16], (const float*)d_in[18]};
    const float* fc1W = (const float*)d_in[19]; const float* fc1b = (const float*)d_in[20];
    const float* fc2W = (const float*)d_in[21]; const float* fc2b = (const float*)d_in[22];
    const float* fc3W = (const float*)d_in[23]; const float* fc3b = (const float*)d_in[24];
    const float* oW   = (const float*)d_in[25]; const float* ob   = (const float*)d_in[26];

    const int N = NNODES, E = NEDGES, B = NPAIRS;
    typedef unsigned short u16;
    char* ws = (char*)d_ws;

    // graph scratch
    unsigned* cnt    = (unsigned*)(ws + 0);
    unsigned* cursor = (unsigned*)(ws + 120064);
    unsigned* rowptr = (unsigned*)(ws + 240128);
    int*      colsrc = (int*)     (ws + 360192);
    float*    dinv   = (float*)   (ws + 2280192);

    // converted weights (hi/lo transposed [Np][Kp])
    u16* W2th = (u16*)(ws + 2400256);  u16* W2tl = (u16*)(ws + 4005888);
    u16* W3th = (u16*)(ws + 5611520);  u16* W3tl = (u16*)(ws + 6070272);
    u16* g1h  = (u16*)(ws + 6529024);  u16* g1l  = (u16*)(ws + 6660096);
    u16* g2h  = (u16*)(ws + 6791168);  u16* g2l  = (u16*)(ws + 6922240);
    u16* g3h  = (u16*)(ws + 7053312);  u16* g3l  = (u16*)(ws + 7184384);
    u16* g4h  = (u16*)(ws + 7315456);  u16* g4l  = (u16*)(ws + 7380992);
    u16* g5h  = (u16*)(ws + 7446528);  u16* g5l  = (u16*)(ws + 7479296);
    u16* f1h  = (u16*)(ws + 7512064);  u16* f1l  = (u16*)(ws + 8036352);
    u16* f2h  = (u16*)(ws + 8560640);  u16* f2l  = (u16*)(ws + 9084928);
    u16* f3h  = (u16*)(ws + 9609216);  u16* f3l  = (u16*)(ws + 9674752);

    // activations
    u16* x2h = (u16*)(ws + 9740288);
    u16* x2l = (u16*)(ws + 25141248);
    // x1 region (overlaid after BB fc3 consumes it)
    const size_t X1 = 40542208;
    u16* x1h = (u16*)(ws + X1);
    u16* x1l = (u16*)(ws + X1 + 53903360);
    // overlay of x1 region:
    float* hW   = (float*)(ws + X1);              // 30,720,000
    u16*   hAh  = (u16*)  (ws + X1 + 30720000);   // 15,400,960
    u16*   hAl  = (u16*)  (ws + X1 + 46120960);
    float* hfin = (float*)(ws + X1 + 61521920);   // 15,360,000
    u16*   xch  = (u16*)  (ws + X1 + 76881920);   // 2,097,152
    u16*   xcl  = (u16*)  (ws + X1 + 78979072);
    u16*   t1h  = (u16*)  (ws + X1 + 81076224);   // 8,388,608
    u16*   t1l  = (u16*)  (ws + X1 + 89464832);
    u16*   t2h  = (u16*)  (ws + X1 + 97853440);   // 2,097,152
    u16*   t2l  = (u16*)  (ws + X1 + 99950592);
    float* t3   = (float*)(ws + X1 + 102047744);  // 1,048,576

    // --- graph prep ---
    hipMemsetAsync(cnt, 0, N * sizeof(unsigned), stream);
    hipMemsetAsync(cursor, 0, N * sizeof(unsigned), stream);
    k_count<<<(E + 255) / 256, 256, 0, stream>>>(le + E, cnt, E);
    k_dinv<<<(N + 255) / 256, 256, 0, stream>>>(cnt, dinv, N);
    k_scan<<<1, 1024, 0, stream>>>(cnt, rowptr, N);
    k_fill<<<(E + 255) / 256, 256, 0, stream>>>(le, le + E, rowptr, cursor, colsrc, E);

    // --- weight conversion ---
    k_wconv<<<3136, 256, 0, stream>>>(W2, W2th, W2tl, 881, 881, 896, 896);
    k_wconv<<<896, 256, 0, stream>>>(W3, W3th, W3tl, 881, 256, 896, 256);
    k_wconv<<<256, 256, 0, stream>>>(gW[0], g1h, g1l, 256, 256, 256, 256);
    k_wconv<<<256, 256, 0, stream>>>(gW[1], g2h, g2l, 256, 256, 256, 256);
    k_wconv<<<256, 256, 0, stream>>>(gW[2], g3h, g3l, 256, 256, 256, 256);
    k_wconv<<<128, 256, 0, stream>>>(gW[3], g4h, g4l, 256, 128, 256, 128);
    k_wconv<<<64, 256, 0, stream>>>(gW[4], g5h, g5l, 128, 128, 128, 128);
    k_wconv<<<1024, 256, 0, stream>>>(fc1W, f1h, f1l, 256, 1024, 256, 1024);
    k_wconv<<<1024, 256, 0, stream>>>(fc2W, f2h, f2l, 1024, 256, 1024, 256);
    k_wconv<<<128, 256, 0, stream>>>(fc3W, f3h, f3l, 256, 64, 256, 128);

    const int MB = (N + 127) / 128;  // 235

    // --- BasicBlock1 ---
    k_mgemm<0, 2, 1><<<dim3(MB, 7), 256, 0, stream>>>(
        cid, 881, 881, nullptr, nullptr, 0, W2th, W2tl, b2, thr,
        nullptr, x1h, x1l, 896, N, 881, 896);
    k_mgemm<1, 1, 1><<<dim3(MB, 2), 256, 0, stream>>>(
        nullptr, 0, 0, x1h, x1l, 896, W3th, W3tl, b3, nullptr,
        nullptr, x2h, x2l, 256, N, 256, 896);

    // --- 5 GCN layers ---
    const u16* wh[5] = {g1h, g2h, g3h, g4h, g5h};
    const u16* wl[5] = {g1l, g2l, g3l, g4l, g5l};
    const int fin[5]  = {256, 256, 256, 256, 128};
    const int fout[5] = {256, 256, 256, 128, 128};
    u16* curh = x2h;  u16* curl = x2l;
    for (int l = 0; l < 5; ++l) {
        k_mgemm<1, 0, 0><<<dim3(MB, fout[l] / 128), 256, 0, stream>>>(
            nullptr, 0, 0, curh, curl, fin[l], wh[l], wl[l], nullptr, nullptr,
            hW, nullptr, nullptr, fout[l], N, fout[l], fin[l]);
        if (l == 4) {
            k_agg<2, 0><<<(N + 3) / 4, 256, 0, stream>>>(hW, dinv, rowptr, colsrc, gB[l],
                                                         hfin, nullptr, nullptr, N);
        } else if (fout[l] == 256) {
            u16* oh = (l & 1) ? x2h : hAh;
            u16* ol = (l & 1) ? x2l : hAl;
            k_agg<4, 1><<<(N + 3) / 4, 256, 0, stream>>>(hW, dinv, rowptr, colsrc, gB[l],
                                                         nullptr, oh, ol, N);
            curh = oh; curl = ol;
        } else {  // l == 3, fout 128
            k_agg<2, 1><<<(N + 3) / 4, 256, 0, stream>>>(hW, dinv, rowptr, colsrc, gB[l],
                                                         nullptr, x2h, x2l, N);
            curh = x2h; curl = x2l;
        }
    }

    // --- pair head ---
    k_pairs<<<(B + 3) / 4, 256, 0, stream>>>(hfin, i1, i2, xch, xcl, B);
    k_mgemm<1, 1, 1><<<dim3(32, 8), 256, 0, stream>>>(
        nullptr, 0, 0, xch, xcl, 256, f1h, f1l, fc1b, nullptr,
        nullptr, t1h, t1l, 1024, B, 1024, 256);
    k_mgemm<1, 1, 1><<<dim3(32, 2), 256, 0, stream>>>(
        nullptr, 0, 0, t1h, t1l, 1024, f2h, f2l, fc2b, nullptr,
        nullptr, t2h, t2l, 256, B, 256, 1024);
    k_mgemm<1, 1, 0><<<dim3(32, 1), 256, 0, stream>>>(
        nullptr, 0, 0, t2h, t2l, 256, f3h, f3l, fc3b, nullptr,
        t3, nullptr, nullptr, 64, B, 64, 256);
    k_out<<<(B + 3) / 4, 256, 0, stream>>>(t3, oW, ob, (float*)d_out, B);
}

// Round 3
// 1363.221 us; speedup vs baseline: 1.8282x; 1.2243x over previous
//
#include <hip/hip_runtime.h>
#include <hip/hip_bf16.h>
#include <math.h>

// ---------------------------------------------------------------------------
// GCN pair scorer, split-bf16 MFMA GEMMs (3-product hi/lo ~ fp32 accuracy).
// Round 3: reg-staged prefetch pipeline, vectorized staging (16B loads,
// ds_write_b128), padded LDS rows (40 u16 = 80B -> 2-way banks = free).
// ---------------------------------------------------------------------------

#define NNODES 30000
#define NEDGES 480000
#define NPAIRS 4096

typedef __attribute__((ext_vector_type(8))) short short8;
typedef __attribute__((ext_vector_type(2))) short short2v;
typedef __attribute__((ext_vector_type(4))) short short4v;
typedef __attribute__((ext_vector_type(4))) float f32x4;
typedef __attribute__((ext_vector_type(2))) float f32x2;
typedef unsigned short u16;

__device__ __forceinline__ u16 f2bf(float x) {
    union { float f; unsigned u; } v; v.f = x;
    unsigned u = v.u;
    return (u16)((u + 0x7FFFu + ((u >> 16) & 1u)) >> 16);
}
__device__ __forceinline__ float bf2f(u16 h) {
    union { float f; unsigned u; } v; v.u = ((unsigned)h) << 16;
    return v.f;
}

// ---------------- graph prep ----------------

__global__ void k_count(const int* __restrict__ dst, unsigned* __restrict__ cnt, int E) {
    int e = blockIdx.x * blockDim.x + threadIdx.x;
    if (e < E) atomicAdd(&cnt[dst[e]], 1u);
}

__global__ void k_dinv(const unsigned* __restrict__ cnt, float* __restrict__ dinv, int N) {
    int n = blockIdx.x * blockDim.x + threadIdx.x;
    if (n < N) {
        float deg = (float)(cnt[n] + 1u);
        dinv[n] = 1.0f / sqrtf(deg);
    }
}

__global__ void k_scan(const unsigned* __restrict__ cnt, unsigned* __restrict__ rowptr, int N) {
    __shared__ unsigned buf[1024];
    __shared__ unsigned carry_s;
    const int tid = threadIdx.x;
    if (tid == 0) { carry_s = 0; rowptr[0] = 0; }
    __syncthreads();
    for (int base = 0; base < N; base += 1024) {
        int i = base + tid;
        unsigned v = (i < N) ? cnt[i] : 0u;
        buf[tid] = v;
        __syncthreads();
        for (int off = 1; off < 1024; off <<= 1) {
            unsigned t = (tid >= off) ? buf[tid - off] : 0u;
            __syncthreads();
            buf[tid] += t;
            __syncthreads();
        }
        unsigned c = carry_s;
        if (i < N) rowptr[i + 1] = c + buf[tid];
        __syncthreads();
        if (tid == 1023) carry_s = c + buf[1023];
        __syncthreads();
    }
}

__global__ void k_fill(const int* __restrict__ src, const int* __restrict__ dst,
                       const unsigned* __restrict__ rowptr, unsigned* __restrict__ cursor,
                       int* __restrict__ colsrc, int E) {
    int e = blockIdx.x * blockDim.x + threadIdx.x;
    if (e < E) {
        int d = dst[e];
        unsigned p = atomicAdd(&cursor[d], 1u);
        colsrc[rowptr[d] + p] = src[e];
    }
}

// ---------------- weight conversion: W[K][N] f32 -> Wt[Np][Kp] bf16 hi/lo ---

__global__ void k_wconv(const float* __restrict__ W, u16* __restrict__ Th,
                        u16* __restrict__ Tl, int K, int N, int Kp, int Np) {
    int idx = blockIdx.x * blockDim.x + threadIdx.x;
    if (idx >= Np * Kp) return;
    int n = idx / Kp, k = idx - n * Kp;
    float v = (n < N && k < K) ? W[(size_t)k * N + n] : 0.f;
    u16 h = f2bf(v);
    Th[idx] = h;
    Tl[idx] = f2bf(v - bf2f(h));
}

// ---------------- split-bf16 MFMA GEMM, reg-staged prefetch ----------------
// ASRC: 0 = f32 A (convert during staging), 1 = bf16 pair A
// EPI : 0 = none, 1 = relu(z+bias), 2 = max(z+bias-thr, 0)
// OUTM: 0 = f32 C, 1 = bf16 hi/lo pair C (cols >= Ntrue zeroed)
// LDS rows padded to 40 u16 (80 B): 16B-aligned slots, 2-way banks (free).

#define LDSW 40

template <int ASRC, int EPI, int OUTM>
__global__ __launch_bounds__(256) void k_mgemm(
    const float* __restrict__ Af, int ldAf, int Ktrue,
    const u16* __restrict__ Ahi, const u16* __restrict__ Alo, int ldA,
    const u16* __restrict__ Bhi, const u16* __restrict__ Blo,
    const float* __restrict__ bias, const float* __restrict__ thrp,
    float* __restrict__ Cf, u16* __restrict__ Chi, u16* __restrict__ Clo,
    int ldC, int M, int Ntrue, int K) {
    __shared__ alignas(16) u16 Ah[128 * LDSW];
    __shared__ alignas(16) u16 Al[128 * LDSW];
    __shared__ alignas(16) u16 Bh[128 * LDSW];
    __shared__ alignas(16) u16 Bl[128 * LDSW];
    const int t = threadIdx.x;
    const int lane = t & 63, w = t >> 6;
    const int wr = w >> 1, wc = w & 1;
    const int r16 = lane & 15, kg = lane >> 4;
    const int bm = blockIdx.x * 128, bn = blockIdx.y * 128;
    // staging mapping: row = t&127, k-chunk = (t>>7)*16
    const int sr = t & 127, cb = (t >> 7) << 4;
    f32x4 acc[4][4] = {};

    float aF[16];          // ASRC=0 staged
    short8 aP[4], bP[4];   // bf16-pair staged

    auto LOAD = [&](int k0) {
        if (ASRC == 0) {
            const int gm = bm + sr;
            const int gmc = gm < M ? gm : M - 1;
            const float* ap = Af + (size_t)gmc * ldAf + k0 + cb;
            const int nv = Ktrue - (k0 + cb);  // > 0 by construction
#pragma unroll
            for (int j = 0; j < 16; ++j) {
                int jc = j < nv ? j : nv - 1;
                aF[j] = ap[jc];
            }
        } else {
            const u16* ah = Ahi + (size_t)(bm + sr) * ldA + k0 + cb;
            const u16* al = Alo + (size_t)(bm + sr) * ldA + k0 + cb;
            aP[0] = *(const short8*)ah;  aP[1] = *(const short8*)(ah + 8);
            aP[2] = *(const short8*)al;  aP[3] = *(const short8*)(al + 8);
        }
        const u16* bh = Bhi + (size_t)(bn + sr) * K + k0 + cb;
        const u16* bl = Blo + (size_t)(bn + sr) * K + k0 + cb;
        bP[0] = *(const short8*)bh;  bP[1] = *(const short8*)(bh + 8);
        bP[2] = *(const short8*)bl;  bP[3] = *(const short8*)(bl + 8);
    };

    auto WRITE = [&](int k0) {
        const int wa = sr * LDSW + cb;
        if (ASRC == 0) {
            const int nv = Ktrue - (k0 + cb);
            short8 h0, h1, l0, l1;
#pragma unroll
            for (int j = 0; j < 8; ++j) {
                float v = (j < nv) ? aF[j] : 0.f;
                u16 hh = f2bf(v);
                h0[j] = (short)hh;
                l0[j] = (short)f2bf(v - bf2f(hh));
            }
#pragma unroll
            for (int j = 0; j < 8; ++j) {
                float v = (j + 8 < nv) ? aF[j + 8] : 0.f;
                u16 hh = f2bf(v);
                h1[j] = (short)hh;
                l1[j] = (short)f2bf(v - bf2f(hh));
            }
            *(short8*)&Ah[wa] = h0;  *(short8*)&Ah[wa + 8] = h1;
            *(short8*)&Al[wa] = l0;  *(short8*)&Al[wa + 8] = l1;
        } else {
            *(short8*)&Ah[wa] = aP[0];  *(short8*)&Ah[wa + 8] = aP[1];
            *(short8*)&Al[wa] = aP[2];  *(short8*)&Al[wa + 8] = aP[3];
        }
        *(short8*)&Bh[wa] = bP[0];  *(short8*)&Bh[wa + 8] = bP[1];
        *(short8*)&Bl[wa] = bP[2];  *(short8*)&Bl[wa + 8] = bP[3];
    };

    LOAD(0);
    for (int k0 = 0; k0 < K; k0 += 32) {
        WRITE(k0);
        __syncthreads();
        if (k0 + 32 < K) LOAD(k0 + 32);   // prefetch: latency hides under MFMA
        short8 fa_h[4], fa_l[4];
#pragma unroll
        for (int mi = 0; mi < 4; ++mi) {
            int off = (wr * 64 + mi * 16 + r16) * LDSW + kg * 8;
            fa_h[mi] = *(const short8*)&Ah[off];
            fa_l[mi] = *(const short8*)&Al[off];
        }
#pragma unroll
        for (int ni = 0; ni < 4; ++ni) {
            int off = (wc * 64 + ni * 16 + r16) * LDSW + kg * 8;
            short8 fb_h = *(const short8*)&Bh[off];
            short8 fb_l = *(const short8*)&Bl[off];
#pragma unroll
            for (int mi = 0; mi < 4; ++mi) {
                acc[mi][ni] = __builtin_amdgcn_mfma_f32_16x16x32_bf16(fa_h[mi], fb_h, acc[mi][ni], 0, 0, 0);
                acc[mi][ni] = __builtin_amdgcn_mfma_f32_16x16x32_bf16(fa_l[mi], fb_h, acc[mi][ni], 0, 0, 0);
                acc[mi][ni] = __builtin_amdgcn_mfma_f32_16x16x32_bf16(fa_h[mi], fb_l, acc[mi][ni], 0, 0, 0);
            }
        }
        __syncthreads();
    }

    const float thr = (EPI == 2) ? *thrp : 0.f;
#pragma unroll
    for (int mi = 0; mi < 4; ++mi) {
#pragma unroll
        for (int ni = 0; ni < 4; ++ni) {
            const int n = bn + wc * 64 + ni * 16 + r16;
#pragma unroll
            for (int i = 0; i < 4; ++i) {
                const int m = bm + wr * 64 + mi * 16 + kg * 4 + i;
                if (m >= M) continue;
                float z = acc[mi][ni][i];
                if (EPI >= 1) {
                    z += (n < Ntrue) ? bias[n] : 0.f;
                    z = (EPI == 1) ? fmaxf(z, 0.f) : fmaxf(z - thr, 0.f);
                }
                if (OUTM == 0) {
                    if (n < Ntrue) Cf[(size_t)m * ldC + n] = z;
                } else {
                    if (n < ldC) {
                        if (n >= Ntrue) z = 0.f;
                        u16 h = f2bf(z);
                        size_t o = (size_t)m * ldC + n;
                        Chi[o] = h;
                        Clo[o] = f2bf(z - bf2f(h));
                    }
                }
            }
        }
    }
}

// ---------------- GCN aggregation (CSR gather, bias+ELU fused) -------------
// FV = F/64 contiguous feats per lane (4 -> float4, 2 -> float2).
// WB=1: write bf16 hi/lo pair; WB=0: write f32.

template <int FV, int WB>
__global__ __launch_bounds__(256) void k_agg(
    const float* __restrict__ hW, const float* __restrict__ dinv,
    const unsigned* __restrict__ rowptr, const int* __restrict__ colsrc,
    const float* __restrict__ bias, float* __restrict__ outf,
    u16* __restrict__ oh, u16* __restrict__ ol, int N) {
    const int wave = threadIdx.x >> 6;
    const int lane = threadIdx.x & 63;
    const int n = blockIdx.x * 4 + wave;
    if (n >= N) return;
    const int F = FV * 64;
    const int fb = lane * FV;
    const float dn = dinv[n];
    float acc[FV];
    if (FV == 4) {
        const f32x4 v = *(const f32x4*)(hW + (size_t)n * F + fb);
#pragma unroll
        for (int j = 0; j < FV; ++j) acc[j] = dn * v[j];
    } else {
        const f32x2 v = *(const f32x2*)(hW + (size_t)n * F + fb);
#pragma unroll
        for (int j = 0; j < FV; ++j) acc[j] = dn * v[j];
    }
    const unsigned beg = rowptr[n], end = rowptr[n + 1];
    for (unsigned idx = beg; idx < end; ++idx) {
        int s = colsrc[idx];
        float wsc = dinv[s];
        if (FV == 4) {
            const f32x4 v = *(const f32x4*)(hW + (size_t)s * F + fb);
#pragma unroll
            for (int j = 0; j < FV; ++j) acc[j] += wsc * v[j];
        } else {
            const f32x2 v = *(const f32x2*)(hW + (size_t)s * F + fb);
#pragma unroll
            for (int j = 0; j < FV; ++j) acc[j] += wsc * v[j];
        }
    }
    float z[FV];
#pragma unroll
    for (int j = 0; j < FV; ++j) {
        float zz = dn * acc[j] + bias[fb + j];
        z[j] = (zz > 0.f) ? zz : expm1f(zz);
    }
    if (WB) {
        if (FV == 4) {
            short4v hv, lv;
#pragma unroll
            for (int j = 0; j < 4; ++j) {
                u16 h = f2bf(z[j]);
                hv[j] = (short)h;
                lv[j] = (short)f2bf(z[j] - bf2f(h));
            }
            *(short4v*)(oh + (size_t)n * F + fb) = hv;
            *(short4v*)(ol + (size_t)n * F + fb) = lv;
        } else {
            short2v hv, lv;
#pragma unroll
            for (int j = 0; j < 2; ++j) {
                u16 h = f2bf(z[j]);
                hv[j] = (short)h;
                lv[j] = (short)f2bf(z[j] - bf2f(h));
            }
            *(short2v*)(oh + (size_t)n * F + fb) = hv;
            *(short2v*)(ol + (size_t)n * F + fb) = lv;
        }
    } else {
        if (FV == 4) {
            f32x4 v;
#pragma unroll
            for (int j = 0; j < 4; ++j) v[j] = z[j];
            *(f32x4*)(outf + (size_t)n * F + fb) = v;
        } else {
            f32x2 v;
#pragma unroll
            for (int j = 0; j < 2; ++j) v[j] = z[j];
            *(f32x2*)(outf + (size_t)n * F + fb) = v;
        }
    }
}

// ---------------- pair readout ----------------

__global__ __launch_bounds__(256) void k_pairs(
    const float* __restrict__ h, const int* __restrict__ i1, const int* __restrict__ i2,
    u16* __restrict__ xh, u16* __restrict__ xl, int B) {
    const int wave = threadIdx.x >> 6;
    const int lane = threadIdx.x & 63;
    const int p = blockIdx.x * 4 + wave;
    if (p >= B) return;
    const int a = i1[p], b = i2[p];
    float v0 = h[(size_t)a * 128 + lane];
    float v1 = h[(size_t)a * 128 + 64 + lane];
    float v2 = h[(size_t)b * 128 + lane];
    float v3 = h[(size_t)b * 128 + 64 + lane];
    float ss = v0 * v0 + v1 * v1 + v2 * v2 + v3 * v3;
#pragma unroll
    for (int o = 32; o > 0; o >>= 1) ss += __shfl_xor(ss, o, 64);
    float scale = 1.0f / fmaxf(sqrtf(ss), 1e-12f);
    size_t o = (size_t)p * 256;
    float vv[4] = {v0 * scale, v1 * scale, v2 * scale, v3 * scale};
#pragma unroll
    for (int j = 0; j < 4; ++j) {
        u16 hh = f2bf(vv[j]);
        xh[o + j * 64 + lane] = hh;
        xl[o + j * 64 + lane] = f2bf(vv[j] - bf2f(hh));
    }
}

__global__ __launch_bounds__(256) void k_out(
    const float* __restrict__ x, const float* __restrict__ W, const float* __restrict__ b,
    float* __restrict__ out, int B) {
    const int wave = threadIdx.x >> 6;
    const int lane = threadIdx.x & 63;
    const int p = blockIdx.x * 4 + wave;
    if (p >= B) return;
    float v = x[(size_t)p * 64 + lane];
    float s0 = v * W[lane * 2 + 0];
    float s1 = v * W[lane * 2 + 1];
#pragma unroll
    for (int o = 32; o > 0; o >>= 1) {
        s0 += __shfl_xor(s0, o, 64);
        s1 += __shfl_xor(s1, o, 64);
    }
    if (lane == 0) {
        out[p * 2 + 0] = s0 + b[0];
        out[p * 2 + 1] = s1 + b[1];
    }
}

// ---------------- launcher ----------------

extern "C" void kernel_launch(void* const* d_in, const int* in_sizes, int n_in,
                              void* d_out, int out_size, void* d_ws, size_t ws_size,
                              hipStream_t stream) {
    const float* cid = (const float*)d_in[0];
    const int* le   = (const int*)d_in[1];
    const int* i1   = (const int*)d_in[2];
    const int* i2   = (const int*)d_in[3];
    const float* thr = (const float*)d_in[4];
    const float* W2 = (const float*)d_in[5];  const float* b2 = (const float*)d_in[6];
    const float* W3 = (const float*)d_in[7];  const float* b3 = (const float*)d_in[8];
    const float* gW[5] = {(const float*)d_in[9],  (const float*)d_in[11], (const float*)d_in[13],
                          (const float*)d_in[15], (const float*)d_in[17]};
    const float* gB[5] = {(const float*)d_in[10], (const float*)d_in[12], (const float*)d_in[14],
                          (const float*)d_in[16], (const float*)d_in[18]};
    const float* fc1W = (const float*)d_in[19]; const float* fc1b = (const float*)d_in[20];
    const float* fc2W = (const float*)d_in[21]; const float* fc2b = (const float*)d_in[22];
    const float* fc3W = (const float*)d_in[23]; const float* fc3b = (const float*)d_in[24];
    const float* oW   = (const float*)d_in[25]; const float* ob   = (const float*)d_in[26];

    const int N = NNODES, E = NEDGES, B = NPAIRS;
    char* ws = (char*)d_ws;

    // graph scratch
    unsigned* cnt    = (unsigned*)(ws + 0);
    unsigned* cursor = (unsigned*)(ws + 120064);
    unsigned* rowptr = (unsigned*)(ws + 240128);
    int*      colsrc = (int*)     (ws + 360192);
    float*    dinv   = (float*)   (ws + 2280192);

    // converted weights (hi/lo transposed [Np][Kp])
    u16* W2th = (u16*)(ws + 2400256);  u16* W2tl = (u16*)(ws + 4005888);
    u16* W3th = (u16*)(ws + 5611520);  u16* W3tl = (u16*)(ws + 6070272);
    u16* g1h  = (u16*)(ws + 6529024);  u16* g1l  = (u16*)(ws + 6660096);
    u16* g2h  = (u16*)(ws + 6791168);  u16* g2l  = (u16*)(ws + 6922240);
    u16* g3h  = (u16*)(ws + 7053312);  u16* g3l  = (u16*)(ws + 7184384);
    u16* g4h  = (u16*)(ws + 7315456);  u16* g4l  = (u16*)(ws + 7380992);
    u16* g5h  = (u16*)(ws + 7446528);  u16* g5l  = (u16*)(ws + 7479296);
    u16* f1h  = (u16*)(ws + 7512064);  u16* f1l  = (u16*)(ws + 8036352);
    u16* f2h  = (u16*)(ws + 8560640);  u16* f2l  = (u16*)(ws + 9084928);
    u16* f3h  = (u16*)(ws + 9609216);  u16* f3l  = (u16*)(ws + 9674752);

    // activations
    u16* x2h = (u16*)(ws + 9740288);
    u16* x2l = (u16*)(ws + 25141248);
    const size_t X1 = 40542208;
    u16* x1h = (u16*)(ws + X1);
    u16* x1l = (u16*)(ws + X1 + 53903360);
    // overlay of x1 region (after BB fc3 consumes it):
    float* hW   = (float*)(ws + X1);              // 30,720,000
    u16*   hAh  = (u16*)  (ws + X1 + 30720000);   // 15,400,960
    u16*   hAl  = (u16*)  (ws + X1 + 46120960);
    float* hfin = (float*)(ws + X1 + 61521920);   // 15,360,000
    u16*   xch  = (u16*)  (ws + X1 + 76881920);
    u16*   xcl  = (u16*)  (ws + X1 + 78979072);
    u16*   t1h  = (u16*)  (ws + X1 + 81076224);
    u16*   t1l  = (u16*)  (ws + X1 + 89464832);
    u16*   t2h  = (u16*)  (ws + X1 + 97853440);
    u16*   t2l  = (u16*)  (ws + X1 + 99950592);
    float* t3   = (float*)(ws + X1 + 102047744);

    // --- graph prep ---
    hipMemsetAsync(cnt, 0, N * sizeof(unsigned), stream);
    hipMemsetAsync(cursor, 0, N * sizeof(unsigned), stream);
    k_count<<<(E + 255) / 256, 256, 0, stream>>>(le + E, cnt, E);
    k_dinv<<<(N + 255) / 256, 256, 0, stream>>>(cnt, dinv, N);
    k_scan<<<1, 1024, 0, stream>>>(cnt, rowptr, N);
    k_fill<<<(E + 255) / 256, 256, 0, stream>>>(le, le + E, rowptr, cursor, colsrc, E);

    // --- weight conversion ---
    k_wconv<<<3136, 256, 0, stream>>>(W2, W2th, W2tl, 881, 881, 896, 896);
    k_wconv<<<896, 256, 0, stream>>>(W3, W3th, W3tl, 881, 256, 896, 256);
    k_wconv<<<256, 256, 0, stream>>>(gW[0], g1h, g1l, 256, 256, 256, 256);
    k_wconv<<<256, 256, 0, stream>>>(gW[1], g2h, g2l, 256, 256, 256, 256);
    k_wconv<<<256, 256, 0, stream>>>(gW[2], g3h, g3l, 256, 256, 256, 256);
    k_wconv<<<128, 256, 0, stream>>>(gW[3], g4h, g4l, 256, 128, 256, 128);
    k_wconv<<<64, 256, 0, stream>>>(gW[4], g5h, g5l, 128, 128, 128, 128);
    k_wconv<<<1024, 256, 0, stream>>>(fc1W, f1h, f1l, 256, 1024, 256, 1024);
    k_wconv<<<1024, 256, 0, stream>>>(fc2W, f2h, f2l, 1024, 256, 1024, 256);
    k_wconv<<<128, 256, 0, stream>>>(fc3W, f3h, f3l, 256, 64, 256, 128);

    const int MB = (N + 127) / 128;  // 235

    // --- BasicBlock1 ---
    k_mgemm<0, 2, 1><<<dim3(MB, 7), 256, 0, stream>>>(
        cid, 881, 881, nullptr, nullptr, 0, W2th, W2tl, b2, thr,
        nullptr, x1h, x1l, 896, N, 881, 896);
    k_mgemm<1, 1, 1><<<dim3(MB, 2), 256, 0, stream>>>(
        nullptr, 0, 0, x1h, x1l, 896, W3th, W3tl, b3, nullptr,
        nullptr, x2h, x2l, 256, N, 256, 896);

    // --- 5 GCN layers ---
    const u16* wh[5] = {g1h, g2h, g3h, g4h, g5h};
    const u16* wl[5] = {g1l, g2l, g3l, g4l, g5l};
    const int fin[5]  = {256, 256, 256, 256, 128};
    const int fout[5] = {256, 256, 256, 128, 128};
    u16* curh = x2h;  u16* curl = x2l;
    for (int l = 0; l < 5; ++l) {
        k_mgemm<1, 0, 0><<<dim3(MB, fout[l] / 128), 256, 0, stream>>>(
            nullptr, 0, 0, curh, curl, fin[l], wh[l], wl[l], nullptr, nullptr,
            hW, nullptr, nullptr, fout[l], N, fout[l], fin[l]);
        if (l == 4) {
            k_agg<2, 0><<<(N + 3) / 4, 256, 0, stream>>>(hW, dinv, rowptr, colsrc, gB[l],
                                                         hfin, nullptr, nullptr, N);
        } else if (fout[l] == 256) {
            u16* oh = (l & 1) ? x2h : hAh;
            u16* ol = (l & 1) ? x2l : hAl;
            k_agg<4, 1><<<(N + 3) / 4, 256, 0, stream>>>(hW, dinv, rowptr, colsrc, gB[l],
                                                         nullptr, oh, ol, N);
            curh = oh; curl = ol;
        } else {  // l == 3, fout 128
            k_agg<2, 1><<<(N + 3) / 4, 256, 0, stream>>>(hW, dinv, rowptr, colsrc, gB[l],
                                                         nullptr, x2h, x2l, N);
            curh = x2h; curl = x2l;
        }
    }

    // --- pair head ---
    k_pairs<<<(B + 3) / 4, 256, 0, stream>>>(hfin, i1, i2, xch, xcl, B);
    k_mgemm<1, 1, 1><<<dim3(32, 8), 256, 0, stream>>>(
        nullptr, 0, 0, xch, xcl, 256, f1h, f1l, fc1b, nullptr,
        nullptr, t1h, t1l, 1024, B, 1024, 256);
    k_mgemm<1, 1, 1><<<dim3(32, 2), 256, 0, stream>>>(
        nullptr, 0, 0, t1h, t1l, 1024, f2h, f2l, fc2b, nullptr,
        nullptr, t2h, t2l, 256, B, 256, 1024);
    k_mgemm<1, 1, 0><<<dim3(32, 1), 256, 0, stream>>>(
        nullptr, 0, 0, t2h, t2l, 256, f3h, f3l, fc3b, nullptr,
        t3, nullptr, nullptr, 64, B, 64, 256);
    k_out<<<(B + 3) / 4, 256, 0, stream>>>(t3, oW, ob, (float*)d_out, B);
}

// Round 4
// 1360.245 us; speedup vs baseline: 1.8322x; 1.0022x over previous
//
#include <hip/hip_runtime.h>
#include <hip/hip_bf16.h>
#include <math.h>

// ---------------------------------------------------------------------------
// GCN pair scorer, split-bf16 MFMA GEMMs (3-product hi/lo ~ fp32 accuracy).
// Round 4: m97 structure — global_load_lds(16B) staging, linear LDS [128][32],
// 2-barrier K-loop, bijective XCD swizzle (contiguous row-chunk per XCD),
// dinv prescaled into GEMM epilogue (agg loop = pure gather+add).
// ---------------------------------------------------------------------------

#define NNODES 30000
#define NEDGES 480000
#define NPAIRS 4096

typedef __attribute__((ext_vector_type(8))) short short8;
typedef __attribute__((ext_vector_type(4))) short short4v;
typedef __attribute__((ext_vector_type(2))) short short2v;
typedef __attribute__((ext_vector_type(4))) float f32x4;
typedef __attribute__((ext_vector_type(2))) float f32x2;
typedef unsigned short u16;

__device__ __forceinline__ u16 f2bf(float x) {
    union { float f; unsigned u; } v; v.f = x;
    unsigned u = v.u;
    return (u16)((u + 0x7FFFu + ((u >> 16) & 1u)) >> 16);
}
__device__ __forceinline__ float bf2f(u16 h) {
    union { float f; unsigned u; } v; v.u = ((unsigned)h) << 16;
    return v.f;
}

// async global->LDS, 16B per lane; LDS dest = wave-uniform base + lane*16
__device__ __forceinline__ void gll16(const u16* g, u16* l) {
    __builtin_amdgcn_global_load_lds(
        (const __attribute__((address_space(1))) unsigned int*)g,
        (__attribute__((address_space(3))) unsigned int*)l, 16, 0, 0);
}

// ---------------- graph prep ----------------

__global__ void k_count(const int* __restrict__ dst, unsigned* __restrict__ cnt, int E) {
    int e = blockIdx.x * blockDim.x + threadIdx.x;
    if (e < E) atomicAdd(&cnt[dst[e]], 1u);
}

__global__ void k_dinv(const unsigned* __restrict__ cnt, float* __restrict__ dinv, int N) {
    int n = blockIdx.x * blockDim.x + threadIdx.x;
    if (n < N) {
        float deg = (float)(cnt[n] + 1u);
        dinv[n] = 1.0f / sqrtf(deg);
    }
}

__global__ void k_scan(const unsigned* __restrict__ cnt, unsigned* __restrict__ rowptr, int N) {
    __shared__ unsigned buf[1024];
    __shared__ unsigned carry_s;
    const int tid = threadIdx.x;
    if (tid == 0) { carry_s = 0; rowptr[0] = 0; }
    __syncthreads();
    for (int base = 0; base < N; base += 1024) {
        int i = base + tid;
        unsigned v = (i < N) ? cnt[i] : 0u;
        buf[tid] = v;
        __syncthreads();
        for (int off = 1; off < 1024; off <<= 1) {
            unsigned t = (tid >= off) ? buf[tid - off] : 0u;
            __syncthreads();
            buf[tid] += t;
            __syncthreads();
        }
        unsigned c = carry_s;
        if (i < N) rowptr[i + 1] = c + buf[tid];
        __syncthreads();
        if (tid == 1023) carry_s = c + buf[1023];
        __syncthreads();
    }
}

__global__ void k_fill(const int* __restrict__ src, const int* __restrict__ dst,
                       const unsigned* __restrict__ rowptr, unsigned* __restrict__ cursor,
                       int* __restrict__ colsrc, int E) {
    int e = blockIdx.x * blockDim.x + threadIdx.x;
    if (e < E) {
        int d = dst[e];
        unsigned p = atomicAdd(&cursor[d], 1u);
        colsrc[rowptr[d] + p] = src[e];
    }
}

// ---------------- weight conversion: W[K][N] f32 -> Wt[Np][Kp] bf16 hi/lo ---

__global__ void k_wconv(const float* __restrict__ W, u16* __restrict__ Th,
                        u16* __restrict__ Tl, int K, int N, int Kp, int Np) {
    int idx = blockIdx.x * blockDim.x + threadIdx.x;
    if (idx >= Np * Kp) return;
    int n = idx / Kp, k = idx - n * Kp;
    float v = (n < N && k < K) ? W[(size_t)k * N + n] : 0.f;
    u16 h = f2bf(v);
    Th[idx] = h;
    Tl[idx] = f2bf(v - bf2f(h));
}

// ---------------- split-bf16 MFMA GEMM, m97 structure ----------------------
// ASRC: 0 = f32 A (reg-convert + ds_write staging), 1 = bf16 pair A (gll)
// EPI : 0 = none, 1 = relu(z+bias), 2 = max(z+bias-thr, 0)
// OUTM: 0 = f32 C, 1 = bf16 hi/lo pair C (cols >= Ntrue zeroed),
//       2 = f32 C scaled by rowscale[m]

template <int ASRC, int EPI, int OUTM>
__global__ __launch_bounds__(256) void k_mgemm(
    const float* __restrict__ Af, int ldAf, int Ktrue,
    const u16* __restrict__ Ahi, const u16* __restrict__ Alo, int ldA,
    const u16* __restrict__ Bhi, const u16* __restrict__ Blo, int ldB,
    const float* __restrict__ bias, const float* __restrict__ thrp,
    const float* __restrict__ rowscale,
    float* __restrict__ Cf, u16* __restrict__ Chi, u16* __restrict__ Clo,
    int ldC, int M, int Ntrue, int K, int gy) {
    __shared__ alignas(16) u16 Ah[128 * 32];
    __shared__ alignas(16) u16 Al[128 * 32];
    __shared__ alignas(16) u16 Bh[128 * 32];
    __shared__ alignas(16) u16 Bl[128 * 32];
    const int t = threadIdx.x;
    const int lane = t & 63, w = t >> 6;
    const int wr = w >> 1, wc = w & 1;
    const int r16 = lane & 15, kg = lane >> 4;
    // bijective XCD swizzle (m204): XCD k gets a contiguous wg chunk;
    // y (col-panel) fastest-varying -> A row-stripe L2-hot within chunk.
    const int nwg = gridDim.x;
    const int q = nwg >> 3, r = nwg & 7;
    const int xcd = blockIdx.x & 7, pos = blockIdx.x >> 3;
    const int wg = (xcd < r ? xcd * (q + 1) : r * (q + 1) + (xcd - r) * q) + pos;
    const int bx = wg / gy, by = wg - bx * gy;
    const int bm = bx * 128, bn = by * 128;
    // gll staging map: wave w covers rows [w*32, w*32+32)
    const int srow = (w << 5) + (lane >> 2);
    const int k8 = (lane & 3) << 3;
    const int lb = w << 11;  // byte base inside each LDS array
    f32x4 acc[4][4] = {};

    for (int k0 = 0; k0 < K; k0 += 32) {
        if (ASRC == 0) {
            // f32 A: thread covers row t>>1, k-half (t&1)*16 (16 elems)
            const int arow = t >> 1, kq = (t & 1) << 4;
            int gm = bm + arow; if (gm >= M) gm = M - 1;
            const size_t base = (size_t)gm * ldAf;
#pragma unroll
            for (int jj = 0; jj < 2; ++jj) {
                short8 hv, lv;
#pragma unroll
                for (int j = 0; j < 8; ++j) {
                    const int k = k0 + kq + jj * 8 + j;
                    float v = (k < Ktrue) ? Af[base + k] : 0.f;
                    u16 hh = f2bf(v);
                    hv[j] = (short)hh;
                    lv[j] = (short)f2bf(v - bf2f(hh));
                }
                *(short8*)&Ah[arow * 32 + kq + jj * 8] = hv;
                *(short8*)&Al[arow * 32 + kq + jj * 8] = lv;
            }
        } else {
            gll16(Ahi + (size_t)(bm + srow) * ldA + k0 + k8, (u16*)((char*)Ah + lb));
            gll16(Ahi + (size_t)(bm + srow + 16) * ldA + k0 + k8, (u16*)((char*)Ah + lb + 1024));
            gll16(Alo + (size_t)(bm + srow) * ldA + k0 + k8, (u16*)((char*)Al + lb));
            gll16(Alo + (size_t)(bm + srow + 16) * ldA + k0 + k8, (u16*)((char*)Al + lb + 1024));
        }
        gll16(Bhi + (size_t)(bn + srow) * ldB + k0 + k8, (u16*)((char*)Bh + lb));
        gll16(Bhi + (size_t)(bn + srow + 16) * ldB + k0 + k8, (u16*)((char*)Bh + lb + 1024));
        gll16(Blo + (size_t)(bn + srow) * ldB + k0 + k8, (u16*)((char*)Bl + lb));
        gll16(Blo + (size_t)(bn + srow + 16) * ldB + k0 + k8, (u16*)((char*)Bl + lb + 1024));
        __syncthreads();
        short8 fah[4], fal[4];
#pragma unroll
        for (int mi = 0; mi < 4; ++mi) {
            const int off = (wr * 64 + mi * 16 + r16) * 32 + kg * 8;
            fah[mi] = *(const short8*)&Ah[off];
            fal[mi] = *(const short8*)&Al[off];
        }
#pragma unroll
        for (int ni = 0; ni < 4; ++ni) {
            const int off = (wc * 64 + ni * 16 + r16) * 32 + kg * 8;
            const short8 fbh = *(const short8*)&Bh[off];
            const short8 fbl = *(const short8*)&Bl[off];
#pragma unroll
            for (int mi = 0; mi < 4; ++mi) {
                acc[mi][ni] = __builtin_amdgcn_mfma_f32_16x16x32_bf16(fah[mi], fbh, acc[mi][ni], 0, 0, 0);
                acc[mi][ni] = __builtin_amdgcn_mfma_f32_16x16x32_bf16(fal[mi], fbh, acc[mi][ni], 0, 0, 0);
                acc[mi][ni] = __builtin_amdgcn_mfma_f32_16x16x32_bf16(fah[mi], fbl, acc[mi][ni], 0, 0, 0);
            }
        }
        __syncthreads();
    }

    const float thr = (EPI == 2) ? *thrp : 0.f;
#pragma unroll
    for (int mi = 0; mi < 4; ++mi) {
#pragma unroll
        for (int i = 0; i < 4; ++i) {
            const int m = bm + wr * 64 + mi * 16 + kg * 4 + i;
            if (m >= M) continue;
            const float rs = (OUTM == 2) ? rowscale[m] : 1.f;
#pragma unroll
            for (int ni = 0; ni < 4; ++ni) {
                const int n = bn + wc * 64 + ni * 16 + r16;
                float z = acc[mi][ni][i];
                if (EPI >= 1) {
                    z += (n < Ntrue) ? bias[n] : 0.f;
                    z = (EPI == 1) ? fmaxf(z, 0.f) : fmaxf(z - thr, 0.f);
                }
                if (OUTM == 0) {
                    if (n < Ntrue) Cf[(size_t)m * ldC + n] = z;
                } else if (OUTM == 2) {
                    if (n < Ntrue) Cf[(size_t)m * ldC + n] = z * rs;
                } else {
                    if (n < ldC) {
                        if (n >= Ntrue) z = 0.f;
                        u16 h = f2bf(z);
                        size_t o = (size_t)m * ldC + n;
                        Chi[o] = h;
                        Clo[o] = f2bf(z - bf2f(h));
                    }
                }
            }
        }
    }
}

// ---------------- GCN aggregation (gather+add over prescaled rows) ---------
// hWs rows already scaled by dinv[src]; out = elu(dinv[n]*(self + sum) + b)

template <int FV, int WB>
__global__ __launch_bounds__(256) void k_agg(
    const float* __restrict__ hWs, const float* __restrict__ dinv,
    const unsigned* __restrict__ rowptr, const int* __restrict__ colsrc,
    const float* __restrict__ bias, float* __restrict__ outf,
    u16* __restrict__ oh, u16* __restrict__ ol, int N) {
    const int wave = threadIdx.x >> 6;
    const int lane = threadIdx.x & 63;
    const int n = blockIdx.x * 4 + wave;
    if (n >= N) return;
    const int F = FV * 64;
    const int fb = lane * FV;
    float acc[FV];
    if (FV == 4) {
        const f32x4 v = *(const f32x4*)(hWs + (size_t)n * F + fb);
#pragma unroll
        for (int j = 0; j < FV; ++j) acc[j] = v[j];
    } else {
        const f32x2 v = *(const f32x2*)(hWs + (size_t)n * F + fb);
#pragma unroll
        for (int j = 0; j < FV; ++j) acc[j] = v[j];
    }
    unsigned idx = rowptr[n];
    const unsigned end = rowptr[n + 1];
    for (; idx + 2 <= end; idx += 2) {
        int s0 = colsrc[idx], s1 = colsrc[idx + 1];
        if (FV == 4) {
            const f32x4 v0 = *(const f32x4*)(hWs + (size_t)s0 * F + fb);
            const f32x4 v1 = *(const f32x4*)(hWs + (size_t)s1 * F + fb);
#pragma unroll
            for (int j = 0; j < FV; ++j) acc[j] += v0[j] + v1[j];
        } else {
            const f32x2 v0 = *(const f32x2*)(hWs + (size_t)s0 * F + fb);
            const f32x2 v1 = *(const f32x2*)(hWs + (size_t)s1 * F + fb);
#pragma unroll
            for (int j = 0; j < FV; ++j) acc[j] += v0[j] + v1[j];
        }
    }
    if (idx < end) {
        int s0 = colsrc[idx];
        if (FV == 4) {
            const f32x4 v0 = *(const f32x4*)(hWs + (size_t)s0 * F + fb);
#pragma unroll
            for (int j = 0; j < FV; ++j) acc[j] += v0[j];
        } else {
            const f32x2 v0 = *(const f32x2*)(hWs + (size_t)s0 * F + fb);
#pragma unroll
            for (int j = 0; j < FV; ++j) acc[j] += v0[j];
        }
    }
    const float dn = dinv[n];
    float z[FV];
#pragma unroll
    for (int j = 0; j < FV; ++j) {
        float zz = dn * acc[j] + bias[fb + j];
        z[j] = (zz > 0.f) ? zz : expm1f(zz);
    }
    if (WB) {
        if (FV == 4) {
            short4v hv, lv;
#pragma unroll
            for (int j = 0; j < 4; ++j) {
                u16 h = f2bf(z[j]);
                hv[j] = (short)h;
                lv[j] = (short)f2bf(z[j] - bf2f(h));
            }
            *(short4v*)(oh + (size_t)n * F + fb) = hv;
            *(short4v*)(ol + (size_t)n * F + fb) = lv;
        } else {
            short2v hv, lv;
#pragma unroll
            for (int j = 0; j < 2; ++j) {
                u16 h = f2bf(z[j]);
                hv[j] = (short)h;
                lv[j] = (short)f2bf(z[j] - bf2f(h));
            }
            *(short2v*)(oh + (size_t)n * F + fb) = hv;
            *(short2v*)(ol + (size_t)n * F + fb) = lv;
        }
    } else {
        if (FV == 4) {
            f32x4 v;
#pragma unroll
            for (int j = 0; j < 4; ++j) v[j] = z[j];
            *(f32x4*)(outf + (size_t)n * F + fb) = v;
        } else {
            f32x2 v;
#pragma unroll
            for (int j = 0; j < 2; ++j) v[j] = z[j];
            *(f32x2*)(outf + (size_t)n * F + fb) = v;
        }
    }
}

// ---------------- pair readout ----------------

__global__ __launch_bounds__(256) void k_pairs(
    const float* __restrict__ h, const int* __restrict__ i1, const int* __restrict__ i2,
    u16* __restrict__ xh, u16* __restrict__ xl, int B) {
    const int wave = threadIdx.x >> 6;
    const int lane = threadIdx.x & 63;
    const int p = blockIdx.x * 4 + wave;
    if (p >= B) return;
    const int a = i1[p], b = i2[p];
    float v0 = h[(size_t)a * 128 + lane];
    float v1 = h[(size_t)a * 128 + 64 + lane];
    float v2 = h[(size_t)b * 128 + lane];
    float v3 = h[(size_t)b * 128 + 64 + lane];
    float ss = v0 * v0 + v1 * v1 + v2 * v2 + v3 * v3;
#pragma unroll
    for (int o = 32; o > 0; o >>= 1) ss += __shfl_xor(ss, o, 64);
    float scale = 1.0f / fmaxf(sqrtf(ss), 1e-12f);
    size_t o = (size_t)p * 256;
    float vv[4] = {v0 * scale, v1 * scale, v2 * scale, v3 * scale};
#pragma unroll
    for (int j = 0; j < 4; ++j) {
        u16 hh = f2bf(vv[j]);
        xh[o + j * 64 + lane] = hh;
        xl[o + j * 64 + lane] = f2bf(vv[j] - bf2f(hh));
    }
}

__global__ __launch_bounds__(256) void k_out(
    const float* __restrict__ x, const float* __restrict__ W, const float* __restrict__ b,
    float* __restrict__ out, int B) {
    const int wave = threadIdx.x >> 6;
    const int lane = threadIdx.x & 63;
    const int p = blockIdx.x * 4 + wave;
    if (p >= B) return;
    float v = x[(size_t)p * 64 + lane];
    float s0 = v * W[lane * 2 + 0];
    float s1 = v * W[lane * 2 + 1];
#pragma unroll
    for (int o = 32; o > 0; o >>= 1) {
        s0 += __shfl_xor(s0, o, 64);
        s1 += __shfl_xor(s1, o, 64);
    }
    if (lane == 0) {
        out[p * 2 + 0] = s0 + b[0];
        out[p * 2 + 1] = s1 + b[1];
    }
}

// ---------------- launcher ----------------

extern "C" void kernel_launch(void* const* d_in, const int* in_sizes, int n_in,
                              void* d_out, int out_size, void* d_ws, size_t ws_size,
                              hipStream_t stream) {
    const float* cid = (const float*)d_in[0];
    const int* le   = (const int*)d_in[1];
    const int* i1   = (const int*)d_in[2];
    const int* i2   = (const int*)d_in[3];
    const float* thr = (const float*)d_in[4];
    const float* W2 = (const float*)d_in[5];  const float* b2 = (const float*)d_in[6];
    const float* W3 = (const float*)d_in[7];  const float* b3 = (const float*)d_in[8];
    const float* gW[5] = {(const float*)d_in[9],  (const float*)d_in[11], (const float*)d_in[13],
                          (const float*)d_in[15], (const float*)d_in[17]};
    const float* gB[5] = {(const float*)d_in[10], (const float*)d_in[12], (const float*)d_in[14],
                          (const float*)d_in[16], (const float*)d_in[18]};
    const float* fc1W = (const float*)d_in[19]; const float* fc1b = (const float*)d_in[20];
    const float* fc2W = (const float*)d_in[21]; const float* fc2b = (const float*)d_in[22];
    const float* fc3W = (const float*)d_in[23]; const float* fc3b = (const float*)d_in[24];
    const float* oW   = (const float*)d_in[25]; const float* ob   = (const float*)d_in[26];

    const int N = NNODES, E = NEDGES, B = NPAIRS;
    char* ws = (char*)d_ws;

    // graph scratch
    unsigned* cnt    = (unsigned*)(ws + 0);
    unsigned* cursor = (unsigned*)(ws + 120064);
    unsigned* rowptr = (unsigned*)(ws + 240128);
    int*      colsrc = (int*)     (ws + 360192);
    float*    dinv   = (float*)   (ws + 2280192);

    // converted weights (hi/lo transposed [Np][Kp])
    u16* W2th = (u16*)(ws + 2400256);  u16* W2tl = (u16*)(ws + 4005888);
    u16* W3th = (u16*)(ws + 5611520);  u16* W3tl = (u16*)(ws + 6070272);
    u16* g1h  = (u16*)(ws + 6529024);  u16* g1l  = (u16*)(ws + 6660096);
    u16* g2h  = (u16*)(ws + 6791168);  u16* g2l  = (u16*)(ws + 6922240);
    u16* g3h  = (u16*)(ws + 7053312);  u16* g3l  = (u16*)(ws + 7184384);
    u16* g4h  = (u16*)(ws + 7315456);  u16* g4l  = (u16*)(ws + 7380992);
    u16* g5h  = (u16*)(ws + 7446528);  u16* g5l  = (u16*)(ws + 7479296);
    u16* f1h  = (u16*)(ws + 7512064);  u16* f1l  = (u16*)(ws + 8036352);
    u16* f2h  = (u16*)(ws + 8560640);  u16* f2l  = (u16*)(ws + 9084928);
    u16* f3h  = (u16*)(ws + 9609216);  u16* f3l  = (u16*)(ws + 9674752);

    // activations (rows padded to 30080)
    u16* x2h = (u16*)(ws + 9740288);              // [30080][256] pair
    u16* x2l = (u16*)(ws + 25141248);
    const size_t X1 = 40542208;
    u16* x1h = (u16*)(ws + X1);                   // [30080][896] pair
    u16* x1l = (u16*)(ws + X1 + 53903360);
    // overlay of x1 region (after BB fc3 consumes x1):
    float* hWs  = (float*)(ws + X1);               // [30080][256] f32 (prescaled)
    u16*   hAh  = (u16*)  (ws + X1 + 30801920);    // [30080][256] pair
    u16*   hAl  = (u16*)  (ws + X1 + 46202880);
    float* hfin = (float*)(ws + X1 + 61603840);    // [30000][128] f32
    u16*   xch  = (u16*)  (ws + X1 + 76963840);    // [4096][256] pair
    u16*   xcl  = (u16*)  (ws + X1 + 79060992);
    u16*   t1h  = (u16*)  (ws + X1 + 81158144);    // [4096][1024] pair
    u16*   t1l  = (u16*)  (ws + X1 + 89546752);
    u16*   t2h  = (u16*)  (ws + X1 + 97935360);    // [4096][256] pair
    u16*   t2l  = (u16*)  (ws + X1 + 100032512);
    float* t3   = (float*)(ws + X1 + 102129664);   // [4096][64] f32

    // --- graph prep ---
    hipMemsetAsync(cnt, 0, N * sizeof(unsigned), stream);
    hipMemsetAsync(cursor, 0, N * sizeof(unsigned), stream);
    k_count<<<(E + 255) / 256, 256, 0, stream>>>(le + E, cnt, E);
    k_dinv<<<(N + 255) / 256, 256, 0, stream>>>(cnt, dinv, N);
    k_scan<<<1, 1024, 0, stream>>>(cnt, rowptr, N);
    k_fill<<<(E + 255) / 256, 256, 0, stream>>>(le, le + E, rowptr, cursor, colsrc, E);

    // --- weight conversion ---
    k_wconv<<<3136, 256, 0, stream>>>(W2, W2th, W2tl, 881, 881, 896, 896);
    k_wconv<<<896, 256, 0, stream>>>(W3, W3th, W3tl, 881, 256, 896, 256);
    k_wconv<<<256, 256, 0, stream>>>(gW[0], g1h, g1l, 256, 256, 256, 256);
    k_wconv<<<256, 256, 0, stream>>>(gW[1], g2h, g2l, 256, 256, 256, 256);
    k_wconv<<<256, 256, 0, stream>>>(gW[2], g3h, g3l, 256, 256, 256, 256);
    k_wconv<<<128, 256, 0, stream>>>(gW[3], g4h, g4l, 256, 128, 256, 128);
    k_wconv<<<64, 256, 0, stream>>>(gW[4], g5h, g5l, 128, 128, 128, 128);
    k_wconv<<<1024, 256, 0, stream>>>(fc1W, f1h, f1l, 256, 1024, 256, 1024);
    k_wconv<<<1024, 256, 0, stream>>>(fc2W, f2h, f2l, 1024, 256, 1024, 256);
    k_wconv<<<128, 256, 0, stream>>>(fc3W, f3h, f3l, 256, 64, 256, 128);

    const int MB = (N + 127) / 128;  // 235

    // --- BasicBlock1 ---
    k_mgemm<0, 2, 1><<<MB * 7, 256, 0, stream>>>(
        cid, 881, 881, nullptr, nullptr, 0, W2th, W2tl, 896, b2, thr, nullptr,
        nullptr, x1h, x1l, 896, N, 881, 896, 7);
    k_mgemm<1, 1, 1><<<MB * 2, 256, 0, stream>>>(
        nullptr, 0, 0, x1h, x1l, 896, W3th, W3tl, 896, b3, nullptr, nullptr,
        nullptr, x2h, x2l, 256, N, 256, 896, 2);

    // --- 5 GCN layers ---
    const u16* wh[5] = {g1h, g2h, g3h, g4h, g5h};
    const u16* wl[5] = {g1l, g2l, g3l, g4l, g5l};
    const int fin[5]  = {256, 256, 256, 256, 128};
    const int fout[5] = {256, 256, 256, 128, 128};
    u16* curh = x2h;  u16* curl = x2l;
    for (int l = 0; l < 5; ++l) {
        const int gy = fout[l] / 128;
        k_mgemm<1, 0, 2><<<MB * gy, 256, 0, stream>>>(
            nullptr, 0, 0, curh, curl, fin[l], wh[l], wl[l], fin[l], nullptr, nullptr, dinv,
            hWs, nullptr, nullptr, fout[l], N, fout[l], fin[l], gy);
        if (l == 4) {
            k_agg<2, 0><<<(N + 3) / 4, 256, 0, stream>>>(hWs, dinv, rowptr, colsrc, gB[l],
                                                         hfin, nullptr, nullptr, N);
        } else if (fout[l] == 256) {
            u16* oh = (l & 1) ? x2h : hAh;
            u16* ol = (l & 1) ? x2l : hAl;
            k_agg<4, 1><<<(N + 3) / 4, 256, 0, stream>>>(hWs, dinv, rowptr, colsrc, gB[l],
                                                         nullptr, oh, ol, N);
            curh = oh; curl = ol;
        } else {  // l == 3, fout 128
            k_agg<2, 1><<<(N + 3) / 4, 256, 0, stream>>>(hWs, dinv, rowptr, colsrc, gB[l],
                                                         nullptr, x2h, x2l, N);
            curh = x2h; curl = x2l;
        }
    }

    // --- pair head ---
    k_pairs<<<(B + 3) / 4, 256, 0, stream>>>(hfin, i1, i2, xch, xcl, B);
    k_mgemm<1, 1, 1><<<32 * 8, 256, 0, stream>>>(
        nullptr, 0, 0, xch, xcl, 256, f1h, f1l, 256, fc1b, nullptr, nullptr,
        nullptr, t1h, t1l, 1024, B, 1024, 256, 8);
    k_mgemm<1, 1, 1><<<32 * 2, 256, 0, stream>>>(
        nullptr, 0, 0, t1h, t1l, 1024, f2h, f2l, 1024, fc2b, nullptr, nullptr,
        nullptr, t2h, t2l, 256, B, 256, 1024, 2);
    k_mgemm<1, 1, 0><<<32 * 1, 256, 0, stream>>>(
        nullptr, 0, 0, t2h, t2l, 256, f3h, f3l, 256, fc3b, nullptr, nullptr,
        t3, nullptr, nullptr, 64, B, 64, 256, 1);
    k_out<<<(B + 3) / 4, 256, 0, stream>>>(t3, oW, ob, (float*)d_out, B);
}

// Round 6
// 1174.328 us; speedup vs baseline: 2.1223x; 1.1583x over previous
//
#include <hip/hip_runtime.h>
#include <hip/hip_bf16.h>
#include <math.h>

// ---------------------------------------------------------------------------
// GCN pair scorer, split-bf16 MFMA GEMMs (3-product hi/lo ~ fp32 accuracy).
// Round 5 (resubmit after infra timeout): cid pre-converted to bf16 hi/lo
// (k_aconv) when ws_size allows -> GEMM1 becomes pure gll-staged (m97
// structure). Fallback ASRC=0 path gets T14 issue-early prefetch.
// Aggregation edge loop unrolled x4.
// ---------------------------------------------------------------------------

#define NNODES 30000
#define NEDGES 480000
#define NPAIRS 4096

typedef __attribute__((ext_vector_type(8))) short short8;
typedef __attribute__((ext_vector_type(4))) short short4v;
typedef __attribute__((ext_vector_type(2))) short short2v;
typedef __attribute__((ext_vector_type(4))) float f32x4;
typedef __attribute__((ext_vector_type(2))) float f32x2;
typedef unsigned short u16;

__device__ __forceinline__ u16 f2bf(float x) {
    union { float f; unsigned u; } v; v.f = x;
    unsigned u = v.u;
    return (u16)((u + 0x7FFFu + ((u >> 16) & 1u)) >> 16);
}
__device__ __forceinline__ float bf2f(u16 h) {
    union { float f; unsigned u; } v; v.u = ((unsigned)h) << 16;
    return v.f;
}

// async global->LDS, 16B per lane; LDS dest = wave-uniform base + lane*16
__device__ __forceinline__ void gll16(const u16* g, u16* l) {
    __builtin_amdgcn_global_load_lds(
        (const __attribute__((address_space(1))) unsigned int*)g,
        (__attribute__((address_space(3))) unsigned int*)l, 16, 0, 0);
}

// ---------------- graph prep ----------------

__global__ void k_count(const int* __restrict__ dst, unsigned* __restrict__ cnt, int E) {
    int e = blockIdx.x * blockDim.x + threadIdx.x;
    if (e < E) atomicAdd(&cnt[dst[e]], 1u);
}

__global__ void k_dinv(const unsigned* __restrict__ cnt, float* __restrict__ dinv, int N) {
    int n = blockIdx.x * blockDim.x + threadIdx.x;
    if (n < N) {
        float deg = (float)(cnt[n] + 1u);
        dinv[n] = 1.0f / sqrtf(deg);
    }
}

__global__ void k_scan(const unsigned* __restrict__ cnt, unsigned* __restrict__ rowptr, int N) {
    __shared__ unsigned buf[1024];
    __shared__ unsigned carry_s;
    const int tid = threadIdx.x;
    if (tid == 0) { carry_s = 0; rowptr[0] = 0; }
    __syncthreads();
    for (int base = 0; base < N; base += 1024) {
        int i = base + tid;
        unsigned v = (i < N) ? cnt[i] : 0u;
        buf[tid] = v;
        __syncthreads();
        for (int off = 1; off < 1024; off <<= 1) {
            unsigned t = (tid >= off) ? buf[tid - off] : 0u;
            __syncthreads();
            buf[tid] += t;
            __syncthreads();
        }
        unsigned c = carry_s;
        if (i < N) rowptr[i + 1] = c + buf[tid];
        __syncthreads();
        if (tid == 1023) carry_s = c + buf[1023];
        __syncthreads();
    }
}

__global__ void k_fill(const int* __restrict__ src, const int* __restrict__ dst,
                       const unsigned* __restrict__ rowptr, unsigned* __restrict__ cursor,
                       int* __restrict__ colsrc, int E) {
    int e = blockIdx.x * blockDim.x + threadIdx.x;
    if (e < E) {
        int d = dst[e];
        unsigned p = atomicAdd(&cursor[d], 1u);
        colsrc[rowptr[d] + p] = src[e];
    }
}

// ---------------- conversions ----------------

__global__ void k_wconv(const float* __restrict__ W, u16* __restrict__ Th,
                        u16* __restrict__ Tl, int K, int N, int Kp, int Np) {
    int idx = blockIdx.x * blockDim.x + threadIdx.x;
    if (idx >= Np * Kp) return;
    int n = idx / Kp, k = idx - n * Kp;
    float v = (n < N && k < K) ? W[(size_t)k * N + n] : 0.f;
    u16 h = f2bf(v);
    Th[idx] = h;
    Tl[idx] = f2bf(v - bf2f(h));
}

// cid [30000][881] f32 -> [30080][896] bf16 hi/lo (pad cols zero)
__global__ void k_aconv(const float* __restrict__ A, u16* __restrict__ Hh,
                        u16* __restrict__ Hl) {
    int idx = blockIdx.x * blockDim.x + threadIdx.x;
    if (idx >= NNODES * 896) return;
    int row = idx / 896, col = idx - row * 896;
    float v = (col < 881) ? A[(size_t)row * 881 + col] : 0.f;
    u16 h = f2bf(v);
    Hh[idx] = h;
    Hl[idx] = f2bf(v - bf2f(h));
}

// ---------------- split-bf16 MFMA GEMM, m97 structure ----------------------
// ASRC: 0 = f32 A (issue-early reg loads + convert + ds_write), 1 = pair A (gll)
// EPI : 0 = none, 1 = relu(z+bias), 2 = max(z+bias-thr, 0)
// OUTM: 0 = f32 C, 1 = bf16 hi/lo pair C (cols >= Ntrue zeroed),
//       2 = f32 C scaled by rowscale[m]

template <int ASRC, int EPI, int OUTM>
__global__ __launch_bounds__(256) void k_mgemm(
    const float* __restrict__ Af, int ldAf, int Ktrue,
    const u16* __restrict__ Ahi, const u16* __restrict__ Alo, int ldA,
    const u16* __restrict__ Bhi, const u16* __restrict__ Blo, int ldB,
    const float* __restrict__ bias, const float* __restrict__ thrp,
    const float* __restrict__ rowscale,
    float* __restrict__ Cf, u16* __restrict__ Chi, u16* __restrict__ Clo,
    int ldC, int M, int Ntrue, int K, int gy) {
    __shared__ alignas(16) u16 Ah[128 * 32];
    __shared__ alignas(16) u16 Al[128 * 32];
    __shared__ alignas(16) u16 Bh[128 * 32];
    __shared__ alignas(16) u16 Bl[128 * 32];
    const int t = threadIdx.x;
    const int lane = t & 63, w = t >> 6;
    const int wr = w >> 1, wc = w & 1;
    const int r16 = lane & 15, kg = lane >> 4;
    // bijective XCD swizzle (m204); y (col-panel) fastest -> A-stripe L2-hot
    const int nwg = gridDim.x;
    const int q = nwg >> 3, r = nwg & 7;
    const int xcd = blockIdx.x & 7, pos = blockIdx.x >> 3;
    const int wg = (xcd < r ? xcd * (q + 1) : r * (q + 1) + (xcd - r) * q) + pos;
    const int bx = wg / gy, by = wg - bx * gy;
    const int bm = bx * 128, bn = by * 128;
    // gll staging map: wave w covers rows [w*32, w*32+32)
    const int srow = (w << 5) + (lane >> 2);
    const int k8 = (lane & 3) << 3;
    const int lb = w << 11;
    f32x4 acc[4][4] = {};

    // ASRC==0 A staging: thread covers row t>>1, k-quarter (t&1)*16
    const int arow = t >> 1, kq = (t & 1) << 4;
    int gmA = bm + arow; if (gmA >= M) gmA = M - 1;
    const float* aBase = (ASRC == 0) ? (Af + (size_t)gmA * ldAf) : nullptr;
    float aR[16];

    auto LOADA = [&](int k0) {   // unconditional loads; garbage cols zeroed at write
#pragma unroll
        for (int j = 0; j < 16; ++j) aR[j] = aBase[k0 + kq + j];
    };
    auto WRITEA = [&](int k0) {
        short8 hv0, lv0, hv1, lv1;
#pragma unroll
        for (int j = 0; j < 8; ++j) {
            float v = (k0 + kq + j < Ktrue) ? aR[j] : 0.f;
            u16 hh = f2bf(v);
            hv0[j] = (short)hh;
            lv0[j] = (short)f2bf(v - bf2f(hh));
        }
#pragma unroll
        for (int j = 0; j < 8; ++j) {
            float v = (k0 + kq + 8 + j < Ktrue) ? aR[8 + j] : 0.f;
            u16 hh = f2bf(v);
            hv1[j] = (short)hh;
            lv1[j] = (short)f2bf(v - bf2f(hh));
        }
        const int wa = arow * 32 + kq;
        *(short8*)&Ah[wa] = hv0;  *(short8*)&Ah[wa + 8] = hv1;
        *(short8*)&Al[wa] = lv0;  *(short8*)&Al[wa + 8] = lv1;
    };

    if (ASRC == 0) LOADA(0);
    for (int k0 = 0; k0 < K; k0 += 32) {
        // staging for tile k0
        gll16(Bhi + (size_t)(bn + srow) * ldB + k0 + k8, (u16*)((char*)Bh + lb));
        gll16(Bhi + (size_t)(bn + srow + 16) * ldB + k0 + k8, (u16*)((char*)Bh + lb + 1024));
        gll16(Blo + (size_t)(bn + srow) * ldB + k0 + k8, (u16*)((char*)Bl + lb));
        gll16(Blo + (size_t)(bn + srow + 16) * ldB + k0 + k8, (u16*)((char*)Bl + lb + 1024));
        if (ASRC == 0) {
            WRITEA(k0);   // compiler waits aR (counted vmcnt keeps gll in flight)
        } else {
            gll16(Ahi + (size_t)(bm + srow) * ldA + k0 + k8, (u16*)((char*)Ah + lb));
            gll16(Ahi + (size_t)(bm + srow + 16) * ldA + k0 + k8, (u16*)((char*)Ah + lb + 1024));
            gll16(Alo + (size_t)(bm + srow) * ldA + k0 + k8, (u16*)((char*)Al + lb));
            gll16(Alo + (size_t)(bm + srow + 16) * ldA + k0 + k8, (u16*)((char*)Al + lb + 1024));
        }
        __syncthreads();
        if (ASRC == 0 && k0 + 32 < K) LOADA(k0 + 32);  // issue early, hide under MFMA
        short8 fah[4], fal[4];
#pragma unroll
        for (int mi = 0; mi < 4; ++mi) {
            const int off = (wr * 64 + mi * 16 + r16) * 32 + kg * 8;
            fah[mi] = *(const short8*)&Ah[off];
            fal[mi] = *(const short8*)&Al[off];
        }
#pragma unroll
        for (int ni = 0; ni < 4; ++ni) {
            const int off = (wc * 64 + ni * 16 + r16) * 32 + kg * 8;
            const short8 fbh = *(const short8*)&Bh[off];
            const short8 fbl = *(const short8*)&Bl[off];
#pragma unroll
            for (int mi = 0; mi < 4; ++mi) {
                acc[mi][ni] = __builtin_amdgcn_mfma_f32_16x16x32_bf16(fah[mi], fbh, acc[mi][ni], 0, 0, 0);
                acc[mi][ni] = __builtin_amdgcn_mfma_f32_16x16x32_bf16(fal[mi], fbh, acc[mi][ni], 0, 0, 0);
                acc[mi][ni] = __builtin_amdgcn_mfma_f32_16x16x32_bf16(fah[mi], fbl, acc[mi][ni], 0, 0, 0);
            }
        }
        __syncthreads();
    }

    const float thr = (EPI == 2) ? *thrp : 0.f;
#pragma unroll
    for (int mi = 0; mi < 4; ++mi) {
#pragma unroll
        for (int i = 0; i < 4; ++i) {
            const int m = bm + wr * 64 + mi * 16 + kg * 4 + i;
            if (m >= M) continue;
            const float rs = (OUTM == 2) ? rowscale[m] : 1.f;
#pragma unroll
            for (int ni = 0; ni < 4; ++ni) {
                const int n = bn + wc * 64 + ni * 16 + r16;
                float z = acc[mi][ni][i];
                if (EPI >= 1) {
                    z += (n < Ntrue) ? bias[n] : 0.f;
                    z = (EPI == 1) ? fmaxf(z, 0.f) : fmaxf(z - thr, 0.f);
                }
                if (OUTM == 0) {
                    if (n < Ntrue) Cf[(size_t)m * ldC + n] = z;
                } else if (OUTM == 2) {
                    if (n < Ntrue) Cf[(size_t)m * ldC + n] = z * rs;
                } else {
                    if (n < ldC) {
                        if (n >= Ntrue) z = 0.f;
                        u16 h = f2bf(z);
                        size_t o = (size_t)m * ldC + n;
                        Chi[o] = h;
                        Clo[o] = f2bf(z - bf2f(h));
                    }
                }
            }
        }
    }
}

// ---------------- GCN aggregation (gather+add over prescaled rows) ---------
// hWs rows already scaled by dinv[src]; out = elu(dinv[n]*(self+sum) + b)

template <int FV, int WB>
__global__ __launch_bounds__(256) void k_agg(
    const float* __restrict__ hWs, const float* __restrict__ dinv,
    const unsigned* __restrict__ rowptr, const int* __restrict__ colsrc,
    const float* __restrict__ bias, float* __restrict__ outf,
    u16* __restrict__ oh, u16* __restrict__ ol, int N) {
    const int wave = threadIdx.x >> 6;
    const int lane = threadIdx.x & 63;
    const int n = blockIdx.x * 4 + wave;
    if (n >= N) return;
    const int F = FV * 64;
    const int fb = lane * FV;
    const float* __restrict__ hbase = hWs + fb;
    float acc[FV];
    {
        if (FV == 4) {
            const f32x4 v = *(const f32x4*)(hbase + (size_t)n * F);
#pragma unroll
            for (int j = 0; j < FV; ++j) acc[j] = v[j];
        } else {
            const f32x2 v = *(const f32x2*)(hbase + (size_t)n * F);
#pragma unroll
            for (int j = 0; j < FV; ++j) acc[j] = v[j];
        }
    }
    unsigned idx = rowptr[n];
    const unsigned end = rowptr[n + 1];
    // unroll-4: 4 independent colsrc loads then 4 independent gathers
    for (; idx + 4 <= end; idx += 4) {
        int s0 = colsrc[idx], s1 = colsrc[idx + 1], s2 = colsrc[idx + 2], s3 = colsrc[idx + 3];
        if (FV == 4) {
            const f32x4 v0 = *(const f32x4*)(hbase + (size_t)s0 * F);
            const f32x4 v1 = *(const f32x4*)(hbase + (size_t)s1 * F);
            const f32x4 v2 = *(const f32x4*)(hbase + (size_t)s2 * F);
            const f32x4 v3 = *(const f32x4*)(hbase + (size_t)s3 * F);
#pragma unroll
            for (int j = 0; j < FV; ++j) acc[j] += (v0[j] + v1[j]) + (v2[j] + v3[j]);
        } else {
            const f32x2 v0 = *(const f32x2*)(hbase + (size_t)s0 * F);
            const f32x2 v1 = *(const f32x2*)(hbase + (size_t)s1 * F);
            const f32x2 v2 = *(const f32x2*)(hbase + (size_t)s2 * F);
            const f32x2 v3 = *(const f32x2*)(hbase + (size_t)s3 * F);
#pragma unroll
            for (int j = 0; j < FV; ++j) acc[j] += (v0[j] + v1[j]) + (v2[j] + v3[j]);
        }
    }
    for (; idx < end; ++idx) {
        int s0 = colsrc[idx];
        if (FV == 4) {
            const f32x4 v0 = *(const f32x4*)(hbase + (size_t)s0 * F);
#pragma unroll
            for (int j = 0; j < FV; ++j) acc[j] += v0[j];
        } else {
            const f32x2 v0 = *(const f32x2*)(hbase + (size_t)s0 * F);
#pragma unroll
            for (int j = 0; j < FV; ++j) acc[j] += v0[j];
        }
    }
    const float dn = dinv[n];
    float z[FV];
#pragma unroll
    for (int j = 0; j < FV; ++j) {
        float zz = dn * acc[j] + bias[fb + j];
        z[j] = (zz > 0.f) ? zz : expm1f(zz);
    }
    if (WB) {
        if (FV == 4) {
            short4v hv, lv;
#pragma unroll
            for (int j = 0; j < 4; ++j) {
                u16 h = f2bf(z[j]);
                hv[j] = (short)h;
                lv[j] = (short)f2bf(z[j] - bf2f(h));
            }
            *(short4v*)(oh + (size_t)n * F + fb) = hv;
            *(short4v*)(ol + (size_t)n * F + fb) = lv;
        } else {
            short2v hv, lv;
#pragma unroll
            for (int j = 0; j < 2; ++j) {
                u16 h = f2bf(z[j]);
                hv[j] = (short)h;
                lv[j] = (short)f2bf(z[j] - bf2f(h));
            }
            *(short2v*)(oh + (size_t)n * F + fb) = hv;
            *(short2v*)(ol + (size_t)n * F + fb) = lv;
        }
    } else {
        if (FV == 4) {
            f32x4 v;
#pragma unroll
            for (int j = 0; j < 4; ++j) v[j] = z[j];
            *(f32x4*)(outf + (size_t)n * F + fb) = v;
        } else {
            f32x2 v;
#pragma unroll
            for (int j = 0; j < 2; ++j) v[j] = z[j];
            *(f32x2*)(outf + (size_t)n * F + fb) = v;
        }
    }
}

// ---------------- pair readout ----------------

__global__ __launch_bounds__(256) void k_pairs(
    const float* __restrict__ h, const int* __restrict__ i1, const int* __restrict__ i2,
    u16* __restrict__ xh, u16* __restrict__ xl, int B) {
    const int wave = threadIdx.x >> 6;
    const int lane = threadIdx.x & 63;
    const int p = blockIdx.x * 4 + wave;
    if (p >= B) return;
    const int a = i1[p], b = i2[p];
    float v0 = h[(size_t)a * 128 + lane];
    float v1 = h[(size_t)a * 128 + 64 + lane];
    float v2 = h[(size_t)b * 128 + lane];
    float v3 = h[(size_t)b * 128 + 64 + lane];
    float ss = v0 * v0 + v1 * v1 + v2 * v2 + v3 * v3;
#pragma unroll
    for (int o = 32; o > 0; o >>= 1) ss += __shfl_xor(ss, o, 64);
    float scale = 1.0f / fmaxf(sqrtf(ss), 1e-12f);
    size_t o = (size_t)p * 256;
    float vv[4] = {v0 * scale, v1 * scale, v2 * scale, v3 * scale};
#pragma unroll
    for (int j = 0; j < 4; ++j) {
        u16 hh = f2bf(vv[j]);
        xh[o + j * 64 + lane] = hh;
        xl[o + j * 64 + lane] = f2bf(vv[j] - bf2f(hh));
    }
}

__global__ __launch_bounds__(256) void k_out(
    const float* __restrict__ x, const float* __restrict__ W, const float* __restrict__ b,
    float* __restrict__ out, int B) {
    const int wave = threadIdx.x >> 6;
    const int lane = threadIdx.x & 63;
    const int p = blockIdx.x * 4 + wave;
    if (p >= B) return;
    float v = x[(size_t)p * 64 + lane];
    float s0 = v * W[lane * 2 + 0];
    float s1 = v * W[lane * 2 + 1];
#pragma unroll
    for (int o = 32; o > 0; o >>= 1) {
        s0 += __shfl_xor(s0, o, 64);
        s1 += __shfl_xor(s1, o, 64);
    }
    if (lane == 0) {
        out[p * 2 + 0] = s0 + b[0];
        out[p * 2 + 1] = s1 + b[1];
    }
}

// ---------------- launcher ----------------

extern "C" void kernel_launch(void* const* d_in, const int* in_sizes, int n_in,
                              void* d_out, int out_size, void* d_ws, size_t ws_size,
                              hipStream_t stream) {
    const float* cid = (const float*)d_in[0];
    const int* le   = (const int*)d_in[1];
    const int* i1   = (const int*)d_in[2];
    const int* i2   = (const int*)d_in[3];
    const float* thr = (const float*)d_in[4];
    const float* W2 = (const float*)d_in[5];  const float* b2 = (const float*)d_in[6];
    const float* W3 = (const float*)d_in[7];  const float* b3 = (const float*)d_in[8];
    const float* gW[5] = {(const float*)d_in[9],  (const float*)d_in[11], (const float*)d_in[13],
                          (const float*)d_in[15], (const float*)d_in[17]};
    const float* gB[5] = {(const float*)d_in[10], (const float*)d_in[12], (const float*)d_in[14],
                          (const float*)d_in[16], (const float*)d_in[18]};
    const float* fc1W = (const float*)d_in[19]; const float* fc1b = (const float*)d_in[20];
    const float* fc2W = (const float*)d_in[21]; const float* fc2b = (const float*)d_in[22];
    const float* fc3W = (const float*)d_in[23]; const float* fc3b = (const float*)d_in[24];
    const float* oW   = (const float*)d_in[25]; const float* ob   = (const float*)d_in[26];

    const int N = NNODES, E = NEDGES, B = NPAIRS;
    char* ws = (char*)d_ws;
    const bool big = ws_size >= 230000000ull;   // pre-convert path needs ~225.4 MB

    // graph scratch + weights (fixed region, 0..9,740,288)
    unsigned* cnt    = (unsigned*)(ws + 0);
    unsigned* cursor = (unsigned*)(ws + 120064);
    unsigned* rowptr = (unsigned*)(ws + 240128);
    int*      colsrc = (int*)     (ws + 360192);
    float*    dinv   = (float*)   (ws + 2280192);
    u16* W2th = (u16*)(ws + 2400256);  u16* W2tl = (u16*)(ws + 4005888);
    u16* W3th = (u16*)(ws + 5611520);  u16* W3tl = (u16*)(ws + 6070272);
    u16* g1h  = (u16*)(ws + 6529024);  u16* g1l  = (u16*)(ws + 6660096);
    u16* g2h  = (u16*)(ws + 6791168);  u16* g2l  = (u16*)(ws + 6922240);
    u16* g3h  = (u16*)(ws + 7053312);  u16* g3l  = (u16*)(ws + 7184384);
    u16* g4h  = (u16*)(ws + 7315456);  u16* g4l  = (u16*)(ws + 7380992);
    u16* g5h  = (u16*)(ws + 7446528);  u16* g5l  = (u16*)(ws + 7479296);
    u16* f1h  = (u16*)(ws + 7512064);  u16* f1l  = (u16*)(ws + 8036352);
    u16* f2h  = (u16*)(ws + 8560640);  u16* f2l  = (u16*)(ws + 9084928);
    u16* f3h  = (u16*)(ws + 9609216);  u16* f3l  = (u16*)(ws + 9674752);

    // activation buffers (two layouts)
    u16 *cidh = nullptr, *cidl = nullptr;
    u16 *x1h, *x1l, *x2h, *x2l, *hAh, *hAl, *xch, *xcl, *t1h, *t1l, *t2h, *t2l;
    float *hWs, *hfin, *t3;
    if (big) {
        const size_t CB = 9740288;             // cid-pair region (dead after gemm1)
        const size_t XB = CB + 2ull * 53903360; // x1-pair region (dead after gemm2)
        cidh = (u16*)(ws + CB);
        cidl = (u16*)(ws + CB + 53903360);
        x1h  = (u16*)(ws + XB);
        x1l  = (u16*)(ws + XB + 53903360);
        // overlay on cid region after gemm1:
        x2h  = (u16*)(ws + CB);
        x2l  = (u16*)(ws + CB + 15400960);
        hWs  = (float*)(ws + CB + 30801920);
        hfin = (float*)(ws + CB + 61603840);
        xch  = (u16*)(ws + CB + 76963840);
        xcl  = (u16*)(ws + CB + 79060992);
        t1h  = (u16*)(ws + CB + 81158144);
        t1l  = (u16*)(ws + CB + 89546752);
        t2h  = (u16*)(ws + CB + 97935360);
        t2l  = (u16*)(ws + CB + 100032512);
        t3   = (float*)(ws + CB + 102129664);
        // overlay on x1 region after gemm2:
        hAh  = (u16*)(ws + XB);
        hAl  = (u16*)(ws + XB + 15400960);
    } else {
        const size_t X1 = 40542208;
        x2h = (u16*)(ws + 9740288);
        x2l = (u16*)(ws + 25141248);
        x1h = (u16*)(ws + X1);
        x1l = (u16*)(ws + X1 + 53903360);
        hWs  = (float*)(ws + X1);
        hAh  = (u16*)  (ws + X1 + 30801920);
        hAl  = (u16*)  (ws + X1 + 46202880);
        hfin = (float*)(ws + X1 + 61603840);
        xch  = (u16*)  (ws + X1 + 76963840);
        xcl  = (u16*)  (ws + X1 + 79060992);
        t1h  = (u16*)  (ws + X1 + 81158144);
        t1l  = (u16*)  (ws + X1 + 89546752);
        t2h  = (u16*)  (ws + X1 + 97935360);
        t2l  = (u16*)  (ws + X1 + 100032512);
        t3   = (float*)(ws + X1 + 102129664);
    }

    // --- graph prep ---
    hipMemsetAsync(cnt, 0, N * sizeof(unsigned), stream);
    hipMemsetAsync(cursor, 0, N * sizeof(unsigned), stream);
    k_count<<<(E + 255) / 256, 256, 0, stream>>>(le + E, cnt, E);
    k_dinv<<<(N + 255) / 256, 256, 0, stream>>>(cnt, dinv, N);
    k_scan<<<1, 1024, 0, stream>>>(cnt, rowptr, N);
    k_fill<<<(E + 255) / 256, 256, 0, stream>>>(le, le + E, rowptr, cursor, colsrc, E);

    // --- weight conversion ---
    k_wconv<<<3136, 256, 0, stream>>>(W2, W2th, W2tl, 881, 881, 896, 896);
    k_wconv<<<896, 256, 0, stream>>>(W3, W3th, W3tl, 881, 256, 896, 256);
    k_wconv<<<256, 256, 0, stream>>>(gW[0], g1h, g1l, 256, 256, 256, 256);
    k_wconv<<<256, 256, 0, stream>>>(gW[1], g2h, g2l, 256, 256, 256, 256);
    k_wconv<<<256, 256, 0, stream>>>(gW[2], g3h, g3l, 256, 256, 256, 256);
    k_wconv<<<128, 256, 0, stream>>>(gW[3], g4h, g4l, 256, 128, 256, 128);
    k_wconv<<<64, 256, 0, stream>>>(gW[4], g5h, g5l, 128, 128, 128, 128);
    k_wconv<<<1024, 256, 0, stream>>>(fc1W, f1h, f1l, 256, 1024, 256, 1024);
    k_wconv<<<1024, 256, 0, stream>>>(fc2W, f2h, f2l, 1024, 256, 1024, 256);
    k_wconv<<<128, 256, 0, stream>>>(fc3W, f3h, f3l, 256, 64, 256, 128);

    const int MB = (N + 127) / 128;  // 235

    // --- BasicBlock1 ---
    if (big) {
        k_aconv<<<(NNODES * 896 + 255) / 256, 256, 0, stream>>>(cid, cidh, cidl);
        k_mgemm<1, 2, 1><<<MB * 7, 256, 0, stream>>>(
            nullptr, 0, 0, cidh, cidl, 896, W2th, W2tl, 896, b2, thr, nullptr,
            nullptr, x1h, x1l, 896, N, 881, 896, 7);
    } else {
        k_mgemm<0, 2, 1><<<MB * 7, 256, 0, stream>>>(
            cid, 881, 881, nullptr, nullptr, 0, W2th, W2tl, 896, b2, thr, nullptr,
            nullptr, x1h, x1l, 896, N, 881, 896, 7);
    }
    k_mgemm<1, 1, 1><<<MB * 2, 256, 0, stream>>>(
        nullptr, 0, 0, x1h, x1l, 896, W3th, W3tl, 896, b3, nullptr, nullptr,
        nullptr, x2h, x2l, 256, N, 256, 896, 2);

    // --- 5 GCN layers ---
    const u16* wh[5] = {g1h, g2h, g3h, g4h, g5h};
    const u16* wl[5] = {g1l, g2l, g3l, g4l, g5l};
    const int fin[5]  = {256, 256, 256, 256, 128};
    const int fout[5] = {256, 256, 256, 128, 128};
    u16* curh = x2h;  u16* curl = x2l;
    for (int l = 0; l < 5; ++l) {
        const int gy = fout[l] / 128;
        k_mgemm<1, 0, 2><<<MB * gy, 256, 0, stream>>>(
            nullptr, 0, 0, curh, curl, fin[l], wh[l], wl[l], fin[l], nullptr, nullptr, dinv,
            hWs, nullptr, nullptr, fout[l], N, fout[l], fin[l], gy);
        if (l == 4) {
            k_agg<2, 0><<<(N + 3) / 4, 256, 0, stream>>>(hWs, dinv, rowptr, colsrc, gB[l],
                                                         hfin, nullptr, nullptr, N);
        } else if (fout[l] == 256) {
            u16* oh = (l & 1) ? x2h : hAh;
            u16* ol = (l & 1) ? x2l : hAl;
            k_agg<4, 1><<<(N + 3) / 4, 256, 0, stream>>>(hWs, dinv, rowptr, colsrc, gB[l],
                                                         nullptr, oh, ol, N);
            curh = oh; curl = ol;
        } else {  // l == 3, fout 128
            k_agg<2, 1><<<(N + 3) / 4, 256, 0, stream>>>(hWs, dinv, rowptr, colsrc, gB[l],
                                                         nullptr, x2h, x2l, N);
            curh = x2h; curl = x2l;
        }
    }

    // --- pair head ---
    k_pairs<<<(B + 3) / 4, 256, 0, stream>>>(hfin, i1, i2, xch, xcl, B);
    k_mgemm<1, 1, 1><<<32 * 8, 256, 0, stream>>>(
        nullptr, 0, 0, xch, xcl, 256, f1h, f1l, 256, fc1b, nullptr, nullptr,
        nullptr, t1h, t1l, 1024, B, 1024, 256, 8);
    k_mgemm<1, 1, 1><<<32 * 2, 256, 0, stream>>>(
        nullptr, 0, 0, t1h, t1l, 1024, f2h, f2l, 1024, fc2b, nullptr, nullptr,
        nullptr, t2h, t2l, 256, B, 256, 1024, 2);
    k_mgemm<1, 1, 0><<<32 * 1, 256, 0, stream>>>(
        nullptr, 0, 0, t2h, t2l, 256, f3h, f3l, 256, fc3b, nullptr, nullptr,
        t3, nullptr, nullptr, 64, B, 64, 256, 1);
    k_out<<<(B + 3) / 4, 256, 0, stream>>>(t3, oW, ob, (float*)d_out, B);
}